// Round 1
// baseline (810.102 us; speedup 1.0000x reference)
//
#include <hip/hip_runtime.h>
#include <math.h>

#define DIM 128
#define DEMB 64

// ---------------- CSR build ----------------

__global__ __launch_bounds__(256) void count_kernel(const int* __restrict__ dst,
                                                    int* __restrict__ counts, int n_edges) {
    int i = blockIdx.x * 256 + threadIdx.x;
    if (i < n_edges) atomicAdd(&counts[dst[i]], 1);
}

__global__ __launch_bounds__(256) void scanA_kernel(const int* __restrict__ counts,
                                                    int* __restrict__ excl,
                                                    int* __restrict__ blocksums, int n) {
    __shared__ int sm[256];
    int tid = threadIdx.x;
    int i = blockIdx.x * 256 + tid;
    int v = (i < n) ? counts[i] : 0;
    sm[tid] = v;
    __syncthreads();
    for (int off = 1; off < 256; off <<= 1) {
        int t = (tid >= off) ? sm[tid - off] : 0;
        __syncthreads();
        if (tid >= off) sm[tid] += t;
        __syncthreads();
    }
    if (i < n) excl[i] = sm[tid] - v;
    if (tid == 255) blocksums[blockIdx.x] = sm[255];
}

__global__ __launch_bounds__(512) void scanB_kernel(int* __restrict__ blocksums, int nb) {
    // nb <= 512 (80000/256 = 313)
    __shared__ int sm[512];
    int tid = threadIdx.x;
    int v = (tid < nb) ? blocksums[tid] : 0;
    sm[tid] = v;
    __syncthreads();
    for (int off = 1; off < 512; off <<= 1) {
        int t = (tid >= off) ? sm[tid - off] : 0;
        __syncthreads();
        if (tid >= off) sm[tid] += t;
        __syncthreads();
    }
    if (tid < nb) blocksums[tid] = sm[tid] - v;  // exclusive block offsets, in place
}

__global__ __launch_bounds__(256) void scanC_kernel(int* __restrict__ rowstart,
                                                    int* __restrict__ cursor,
                                                    const int* __restrict__ blockoffs, int n) {
    int i = blockIdx.x * 256 + threadIdx.x;
    if (i < n) {
        int r = rowstart[i] + blockoffs[i >> 8];
        rowstart[i] = r;
        cursor[i] = r;
    }
}

__global__ __launch_bounds__(256) void scatter_kernel(const int* __restrict__ src,
                                                      const int* __restrict__ dst,
                                                      int* __restrict__ cursor,
                                                      int* __restrict__ ssorted, int n_edges) {
    int i = blockIdx.x * 256 + threadIdx.x;
    if (i < n_edges) {
        int p = atomicAdd(&cursor[dst[i]], 1);
        ssorted[p] = src[i];
    }
}

// ---------------- GCN layer 1: mean-aggregate x into A (wave per node) ----------------

__global__ __launch_bounds__(256) void agg_kernel(const float* __restrict__ x,
                                                  const int* __restrict__ rowstart,
                                                  const int* __restrict__ counts,
                                                  const int* __restrict__ ssorted,
                                                  float* __restrict__ A, int n_nodes) {
    int wave = (blockIdx.x * 256 + threadIdx.x) >> 6;
    int lane = threadIdx.x & 63;
    if (wave >= n_nodes) return;
    int base = rowstart[wave];
    int deg = counts[wave];
    float2 acc = {0.f, 0.f};
    const float* xp = x + 2 * lane;
    for (int j = 0; j < deg; j++) {
        int s = ssorted[base + j];
        float2 v = *reinterpret_cast<const float2*>(xp + (size_t)s * DIM);
        acc.x += v.x;
        acc.y += v.y;
    }
    float inv = 1.f / fmaxf((float)deg, 1.f);
    acc.x *= inv;
    acc.y *= inv;
    *reinterpret_cast<float2*>(A + (size_t)wave * DIM + 2 * lane) = acc;
}

// ---------------- h = relu(A @ W1 + b1), 32 rows per block, W1 in LDS ----------------

__global__ __launch_bounds__(256) void gemm1_kernel(const float* __restrict__ A,
                                                    const float* __restrict__ W1,
                                                    const float* __restrict__ b1,
                                                    float* __restrict__ H, int n_rows) {
    __shared__ float W1s[DIM * DIM];  // 64 KB
    __shared__ float As[32 * DIM];    // 16 KB
    int tid = threadIdx.x;
    for (int i = 0; i < 16; i++) {
        int idx = (i * 256 + tid) * 4;
        *reinterpret_cast<float4*>(&W1s[idx]) = *reinterpret_cast<const float4*>(&W1[idx]);
    }
    int r0 = blockIdx.x * 32;
    for (int i = 0; i < 4; i++) {
        int idx = (i * 256 + tid) * 4;
        int gr = r0 + idx / DIM;
        float4 vv = {0, 0, 0, 0};
        if (gr < n_rows) vv = *reinterpret_cast<const float4*>(&A[(size_t)r0 * DIM + idx]);
        *reinterpret_cast<float4*>(&As[idx]) = vv;
    }
    __syncthreads();
    int tx = tid & 31, ty = tid >> 5;
    float4 b = *reinterpret_cast<const float4*>(&b1[tx * 4]);
    float acc[4][4];
#pragma unroll
    for (int i = 0; i < 4; i++) {
        acc[i][0] = b.x; acc[i][1] = b.y; acc[i][2] = b.z; acc[i][3] = b.w;
    }
#pragma unroll 4
    for (int k = 0; k < DIM; k++) {
        float4 w = *reinterpret_cast<const float4*>(&W1s[k * DIM + tx * 4]);
#pragma unroll
        for (int i = 0; i < 4; i++) {
            float a = As[(ty * 4 + i) * DIM + k];
            acc[i][0] += a * w.x;
            acc[i][1] += a * w.y;
            acc[i][2] += a * w.z;
            acc[i][3] += a * w.w;
        }
    }
#pragma unroll
    for (int i = 0; i < 4; i++) {
        int r = r0 + ty * 4 + i;
        if (r < n_rows) {
            float4 o;
            o.x = fmaxf(acc[i][0], 0.f);
            o.y = fmaxf(acc[i][1], 0.f);
            o.z = fmaxf(acc[i][2], 0.f);
            o.w = fmaxf(acc[i][3], 0.f);
            *reinterpret_cast<float4*>(&H[(size_t)r * DIM + tx * 4]) = o;
        }
    }
}

// ------- GCN layer 2 only at target nodes: aggregate h, then @W2 + b2 (wave per target) -------

__global__ __launch_bounds__(256) void target_kernel(const float* __restrict__ H,
                                                     const float* __restrict__ W2,
                                                     const float* __restrict__ b2,
                                                     const int* __restrict__ rowstart,
                                                     const int* __restrict__ counts,
                                                     const int* __restrict__ ssorted,
                                                     const int* __restrict__ dnum,
                                                     const int* __restrict__ tf_idx,
                                                     const int* __restrict__ gene_idx,
                                                     float* __restrict__ emb, int T, int ntar) {
    __shared__ float W2s[DIM * DEMB];  // 32 KB
    __shared__ float aggS[4][DIM];
    int tid = threadIdx.x;
    for (int i = 0; i < 8; i++) {
        int idx = (i * 256 + tid) * 4;
        *reinterpret_cast<float4*>(&W2s[idx]) = *reinterpret_cast<const float4*>(&W2[idx]);
    }
    int wv = tid >> 6, lane = tid & 63;
    int i = blockIdx.x * 4 + wv;
    int num = dnum[0];
    if (i < ntar) {
        int idx = (i < T) ? tf_idx[i] : gene_idx[i - T];
        int node = num + idx;
        int base = rowstart[node];
        int deg = counts[node];
        float2 acc = {0.f, 0.f};
        const float* hp = H + 2 * lane;
        for (int j = 0; j < deg; j++) {
            int s = ssorted[base + j];
            float2 v = *reinterpret_cast<const float2*>(hp + (size_t)s * DIM);
            acc.x += v.x;
            acc.y += v.y;
        }
        float inv = 1.f / fmaxf((float)deg, 1.f);
        float2 st = {acc.x * inv, acc.y * inv};
        *reinterpret_cast<float2*>(&aggS[wv][2 * lane]) = st;
    }
    __syncthreads();
    if (i < ntar) {
        float e = b2[lane];
#pragma unroll 4
        for (int k = 0; k < DIM; k++) e += aggS[wv][k] * W2s[k * DEMB + lane];
        emb[(size_t)i * DEMB + lane] = e;
    }
}

// ------- AB precompute: rows 0..T-1 = tf_emb@Wm1_top + bm1 ; rows T.. = g_emb@Wm1_bot -------

__global__ __launch_bounds__(128) void ab_kernel(const float* __restrict__ emb,
                                                 const float* __restrict__ Wm1,
                                                 const float* __restrict__ bm1,
                                                 float* __restrict__ AB, int T, int ntar) {
    int i = blockIdx.x;
    int j = threadIdx.x;
    if (i >= ntar) return;
    const float* e = emb + (size_t)i * DEMB;
    int base = (i < T) ? 0 : DEMB;
    float acc = (i < T) ? bm1[j] : 0.f;
#pragma unroll 4
    for (int k = 0; k < DEMB; k++) acc += e[k] * Wm1[(size_t)(base + k) * DIM + j];
    AB[(size_t)i * DIM + j] = acc;
}

// ------- final: out[t,g,:] = softmax(relu(tfA[t]+gB[g]) @ Wm2 + bm2) -------

__global__ __launch_bounds__(256) void final_kernel(const float* __restrict__ AB,
                                                    const float* __restrict__ Wm2,
                                                    const float* __restrict__ bm2,
                                                    float* __restrict__ out, int T, int G) {
    __shared__ float tfAs[8 * DIM];  // 4 KB
    __shared__ float wm2s[DIM * 2];
    int tid = threadIdx.x;
    int t0 = blockIdx.y * 8;
    int g0 = blockIdx.x * 256;
    {
        int idx = tid * 4;
        int t = t0 + idx / DIM;
        float4 v = {0, 0, 0, 0};
        if (t < T) v = *reinterpret_cast<const float4*>(&AB[(size_t)t0 * DIM + idx]);
        *reinterpret_cast<float4*>(&tfAs[idx]) = v;
    }
    wm2s[tid] = Wm2[tid];  // 256 floats
    __syncthreads();
    int g = g0 + tid;
    int gc = min(g, G - 1);
    const float4* gp = reinterpret_cast<const float4*>(AB + (size_t)(T + gc) * DIM);
    float acc[8][2];
#pragma unroll
    for (int t = 0; t < 8; t++) { acc[t][0] = 0.f; acc[t][1] = 0.f; }
    for (int kc = 0; kc < 16; kc++) {
        float4 a4 = gp[kc * 2];
        float4 b4 = gp[kc * 2 + 1];
        float gv[8] = {a4.x, a4.y, a4.z, a4.w, b4.x, b4.y, b4.z, b4.w};
#pragma unroll
        for (int k8 = 0; k8 < 8; k8++) {
            int k = kc * 8 + k8;
            float w0 = wm2s[2 * k];
            float w1 = wm2s[2 * k + 1];
#pragma unroll
            for (int t = 0; t < 8; t++) {
                float a = tfAs[t * DIM + k] + gv[k8];
                float r = fmaxf(a, 0.f);
                acc[t][0] += r * w0;
                acc[t][1] += r * w1;
            }
        }
    }
    if (g < G) {
        float bb0 = bm2[0], bb1 = bm2[1];
#pragma unroll
        for (int t = 0; t < 8; t++) {
            if (t0 + t < T) {
                float l0 = acc[t][0] + bb0, l1 = acc[t][1] + bb1;
                float m = fmaxf(l0, l1);
                float e0 = __expf(l0 - m), e1 = __expf(l1 - m);
                float inv = 1.f / (e0 + e1);
                float2 r = {e0 * inv, e1 * inv};
                *reinterpret_cast<float2*>(&out[((size_t)(t0 + t) * G + g) * 2]) = r;
            }
        }
    }
}

// ---------------- launcher ----------------

extern "C" void kernel_launch(void* const* d_in, const int* in_sizes, int n_in,
                              void* d_out, int out_size, void* d_ws, size_t ws_size,
                              hipStream_t stream) {
    const float* x    = (const float*)d_in[0];
    const float* W1   = (const float*)d_in[1];
    const float* b1   = (const float*)d_in[2];
    const float* W2   = (const float*)d_in[3];
    const float* b2   = (const float*)d_in[4];
    const float* Wm1  = (const float*)d_in[5];
    const float* bm1  = (const float*)d_in[6];
    const float* Wm2  = (const float*)d_in[7];
    const float* bm2  = (const float*)d_in[8];
    const int* ei     = (const int*)d_in[9];
    const int* dnum   = (const int*)d_in[10];
    const int* tfidx  = (const int*)d_in[11];
    const int* geidx  = (const int*)d_in[12];
    float* out = (float*)d_out;

    int n_nodes = in_sizes[0] / DIM;
    int n_edges = in_sizes[9] / 2;
    int T = in_sizes[11];
    int G = in_sizes[12];
    int ntar = T + G;
    const int* srcp = ei;
    const int* dstp = ei + n_edges;

    char* w = (char*)d_ws;
    size_t o = 0;
    auto alloc = [&](size_t bytes) {
        void* p = w + o;
        o += (bytes + 255) & ~(size_t)255;
        return p;
    };
    float* H       = (float*)alloc((size_t)n_nodes * DIM * 4);  // 41 MB
    float* A       = (float*)alloc((size_t)n_nodes * DIM * 4);  // 41 MB (reused below)
    int* ssorted   = (int*)alloc((size_t)n_edges * 4);          // 10.24 MB
    int* counts    = (int*)alloc((size_t)n_nodes * 4);
    int* rowstart  = (int*)alloc((size_t)n_nodes * 4);
    int* cursor    = (int*)alloc((size_t)n_nodes * 4);
    int* blockoffs = (int*)alloc(4096);
    // overlays on A (A is dead after gemm1): emb (2.1 MB) at A, AB (4.2 MB) at A+8MB
    float* emb = A;
    float* AB  = A + (8u * 1024u * 1024u / 4u);

    hipMemsetAsync(counts, 0, (size_t)n_nodes * 4, stream);

    int ge = (n_edges + 255) / 256;
    int nb = (n_nodes + 255) / 256;
    count_kernel<<<ge, 256, 0, stream>>>(dstp, counts, n_edges);
    scanA_kernel<<<nb, 256, 0, stream>>>(counts, rowstart, blockoffs, n_nodes);
    scanB_kernel<<<1, 512, 0, stream>>>(blockoffs, nb);
    scanC_kernel<<<nb, 256, 0, stream>>>(rowstart, cursor, blockoffs, n_nodes);
    scatter_kernel<<<ge, 256, 0, stream>>>(srcp, dstp, cursor, ssorted, n_edges);

    agg_kernel<<<(n_nodes + 3) / 4, 256, 0, stream>>>(x, rowstart, counts, ssorted, A, n_nodes);
    gemm1_kernel<<<(n_nodes + 31) / 32, 256, 0, stream>>>(A, W1, b1, H, n_nodes);
    target_kernel<<<(ntar + 3) / 4, 256, 0, stream>>>(H, W2, b2, rowstart, counts, ssorted,
                                                      dnum, tfidx, geidx, emb, T, ntar);
    ab_kernel<<<ntar, 128, 0, stream>>>(emb, Wm1, bm1, AB, T, ntar);
    final_kernel<<<dim3((G + 255) / 256, (T + 7) / 8), 256, 0, stream>>>(AB, Wm2, bm2, out, T, G);
}

// Round 2
// 665.364 us; speedup vs baseline: 1.2175x; 1.2175x over previous
//
#include <hip/hip_runtime.h>
#include <math.h>

#define DIM 128
#define DEMB 64

// ---------------- bf16 pack/unpack helpers ----------------

__device__ __forceinline__ unsigned pack_bf16x2(float a, float b) {
    unsigned ua = __float_as_uint(a);
    unsigned ub = __float_as_uint(b);
    ua = (ua + 0x7fffu + ((ua >> 16) & 1u)) >> 16;          // low half  = bf16(a)
    ub = (ub + 0x7fffu + ((ub >> 16) & 1u)) & 0xffff0000u;  // high half = bf16(b)
    return ua | ub;
}
__device__ __forceinline__ float lo_bf16(unsigned v) { return __uint_as_float(v << 16); }
__device__ __forceinline__ float hi_bf16(unsigned v) { return __uint_as_float(v & 0xffff0000u); }

// ---------------- convert x (f32) -> packed bf16 ----------------

__global__ __launch_bounds__(256) void convert_kernel(const float* __restrict__ in,
                                                      unsigned* __restrict__ out, int n2) {
    int i = blockIdx.x * 256 + threadIdx.x;
    int stride = gridDim.x * 256;
    for (; i < n2; i += stride) {
        float2 v = reinterpret_cast<const float2*>(in)[i];
        out[i] = pack_bf16x2(v.x, v.y);
    }
}

// ---------------- CSR build ----------------

__global__ __launch_bounds__(256) void count_kernel(const int* __restrict__ dst,
                                                    int* __restrict__ counts, int n_edges) {
    int i = blockIdx.x * 256 + threadIdx.x;
    if (i < n_edges) atomicAdd(&counts[dst[i]], 1);
}

__global__ __launch_bounds__(256) void scanA_kernel(const int* __restrict__ counts,
                                                    int* __restrict__ excl,
                                                    int* __restrict__ blocksums, int n) {
    __shared__ int sm[256];
    int tid = threadIdx.x;
    int i = blockIdx.x * 256 + tid;
    int v = (i < n) ? counts[i] : 0;
    sm[tid] = v;
    __syncthreads();
    for (int off = 1; off < 256; off <<= 1) {
        int t = (tid >= off) ? sm[tid - off] : 0;
        __syncthreads();
        if (tid >= off) sm[tid] += t;
        __syncthreads();
    }
    if (i < n) excl[i] = sm[tid] - v;
    if (tid == 255) blocksums[blockIdx.x] = sm[255];
}

__global__ __launch_bounds__(512) void scanB_kernel(int* __restrict__ blocksums, int nb) {
    __shared__ int sm[512];
    int tid = threadIdx.x;
    int v = (tid < nb) ? blocksums[tid] : 0;
    sm[tid] = v;
    __syncthreads();
    for (int off = 1; off < 512; off <<= 1) {
        int t = (tid >= off) ? sm[tid - off] : 0;
        __syncthreads();
        if (tid >= off) sm[tid] += t;
        __syncthreads();
    }
    if (tid < nb) blocksums[tid] = sm[tid] - v;
}

__global__ __launch_bounds__(256) void scanC_kernel(int* __restrict__ rowstart,
                                                    int* __restrict__ cursor,
                                                    const int* __restrict__ blockoffs, int n) {
    int i = blockIdx.x * 256 + threadIdx.x;
    if (i < n) {
        int r = rowstart[i] + blockoffs[i >> 8];
        rowstart[i] = r;
        cursor[i] = r;
    }
}

__global__ __launch_bounds__(256) void scatter_kernel(const int* __restrict__ src,
                                                      const int* __restrict__ dst,
                                                      int* __restrict__ cursor,
                                                      int* __restrict__ ssorted, int n_edges) {
    int i = blockIdx.x * 256 + threadIdx.x;
    if (i < n_edges) {
        int p = atomicAdd(&cursor[dst[i]], 1);
        ssorted[p] = src[i];
    }
}

// ------- GCN layer 1 aggregate: mean over bf16 rows of xh (wave per node) -------

__global__ __launch_bounds__(256) void agg_kernel(const unsigned* __restrict__ xh,
                                                  const int* __restrict__ rowstart,
                                                  const int* __restrict__ counts,
                                                  const int* __restrict__ ssorted,
                                                  float* __restrict__ A, int n_nodes) {
    int wave = (blockIdx.x * 256 + threadIdx.x) >> 6;
    int lane = threadIdx.x & 63;
    if (wave >= n_nodes) return;
    int base = rowstart[wave];
    int deg = counts[wave];
    const unsigned* xp = xh + lane;  // row stride = 64 uints (128 bf16)
    float ax = 0.f, ay = 0.f;
    int j = 0;
    for (; j + 4 <= deg; j += 4) {
        int s0 = ssorted[base + j];
        int s1 = ssorted[base + j + 1];
        int s2 = ssorted[base + j + 2];
        int s3 = ssorted[base + j + 3];
        unsigned v0 = xp[(size_t)s0 * 64];
        unsigned v1 = xp[(size_t)s1 * 64];
        unsigned v2 = xp[(size_t)s2 * 64];
        unsigned v3 = xp[(size_t)s3 * 64];
        ax += (lo_bf16(v0) + lo_bf16(v1)) + (lo_bf16(v2) + lo_bf16(v3));
        ay += (hi_bf16(v0) + hi_bf16(v1)) + (hi_bf16(v2) + hi_bf16(v3));
    }
    for (; j < deg; j++) {
        int s = ssorted[base + j];
        unsigned v = xp[(size_t)s * 64];
        ax += lo_bf16(v);
        ay += hi_bf16(v);
    }
    float inv = 1.f / fmaxf((float)deg, 1.f);
    float2 st = {ax * inv, ay * inv};
    *reinterpret_cast<float2*>(A + (size_t)wave * DIM + 2 * lane) = st;
}

// ------- H = relu(A @ W1 + b1)  (f32 compute, packed-bf16 output) -------

__global__ __launch_bounds__(256) void gemm1_kernel(const float* __restrict__ A,
                                                    const float* __restrict__ W1,
                                                    const float* __restrict__ b1,
                                                    unsigned* __restrict__ Hh, int n_rows) {
    __shared__ float W1s[DIM * DIM];  // 64 KB
    __shared__ float As[32 * DIM];    // 16 KB
    int tid = threadIdx.x;
    for (int i = 0; i < 16; i++) {
        int idx = (i * 256 + tid) * 4;
        *reinterpret_cast<float4*>(&W1s[idx]) = *reinterpret_cast<const float4*>(&W1[idx]);
    }
    int r0 = blockIdx.x * 32;
    for (int i = 0; i < 4; i++) {
        int idx = (i * 256 + tid) * 4;
        int gr = r0 + (idx >> 7);
        float4 vv = {0, 0, 0, 0};
        if (gr < n_rows) vv = *reinterpret_cast<const float4*>(&A[(size_t)r0 * DIM + idx]);
        *reinterpret_cast<float4*>(&As[idx]) = vv;
    }
    __syncthreads();
    int tx = tid & 31, ty = tid >> 5;
    float4 b = *reinterpret_cast<const float4*>(&b1[tx * 4]);
    float acc[4][4];
#pragma unroll
    for (int i = 0; i < 4; i++) {
        acc[i][0] = b.x; acc[i][1] = b.y; acc[i][2] = b.z; acc[i][3] = b.w;
    }
#pragma unroll 8
    for (int kc = 0; kc < 32; kc++) {
        int k = kc * 4;
        float4 w0 = *reinterpret_cast<const float4*>(&W1s[(k + 0) * DIM + tx * 4]);
        float4 w1 = *reinterpret_cast<const float4*>(&W1s[(k + 1) * DIM + tx * 4]);
        float4 w2 = *reinterpret_cast<const float4*>(&W1s[(k + 2) * DIM + tx * 4]);
        float4 w3 = *reinterpret_cast<const float4*>(&W1s[(k + 3) * DIM + tx * 4]);
#pragma unroll
        for (int i = 0; i < 4; i++) {
            float4 a = *reinterpret_cast<const float4*>(&As[(ty * 4 + i) * DIM + k]);
            acc[i][0] += a.x * w0.x; acc[i][1] += a.x * w0.y; acc[i][2] += a.x * w0.z; acc[i][3] += a.x * w0.w;
            acc[i][0] += a.y * w1.x; acc[i][1] += a.y * w1.y; acc[i][2] += a.y * w1.z; acc[i][3] += a.y * w1.w;
            acc[i][0] += a.z * w2.x; acc[i][1] += a.z * w2.y; acc[i][2] += a.z * w2.z; acc[i][3] += a.z * w2.w;
            acc[i][0] += a.w * w3.x; acc[i][1] += a.w * w3.y; acc[i][2] += a.w * w3.z; acc[i][3] += a.w * w3.w;
        }
    }
#pragma unroll
    for (int i = 0; i < 4; i++) {
        int r = r0 + ty * 4 + i;
        if (r < n_rows) {
            float o0 = fmaxf(acc[i][0], 0.f);
            float o1 = fmaxf(acc[i][1], 0.f);
            float o2 = fmaxf(acc[i][2], 0.f);
            float o3 = fmaxf(acc[i][3], 0.f);
            uint2 pk = {pack_bf16x2(o0, o1), pack_bf16x2(o2, o3)};
            *reinterpret_cast<uint2*>(&Hh[(size_t)r * 64 + tx * 2]) = pk;
        }
    }
}

// ------- GCN layer 2 at target nodes only: mean-agg of Hh then @W2 + b2 -------

__global__ __launch_bounds__(256) void target_kernel(const unsigned* __restrict__ Hh,
                                                     const float* __restrict__ W2,
                                                     const float* __restrict__ b2,
                                                     const int* __restrict__ rowstart,
                                                     const int* __restrict__ counts,
                                                     const int* __restrict__ ssorted,
                                                     const int* __restrict__ dnum,
                                                     const int* __restrict__ tf_idx,
                                                     const int* __restrict__ gene_idx,
                                                     float* __restrict__ emb, int T, int ntar) {
    __shared__ float W2s[DIM * DEMB];  // 32 KB
    __shared__ float aggS[4][DIM];
    int tid = threadIdx.x;
    for (int i = 0; i < 8; i++) {
        int idx = (i * 256 + tid) * 4;
        *reinterpret_cast<float4*>(&W2s[idx]) = *reinterpret_cast<const float4*>(&W2[idx]);
    }
    int wv = tid >> 6, lane = tid & 63;
    int i = blockIdx.x * 4 + wv;
    int num = dnum[0];
    if (i < ntar) {
        int idx = (i < T) ? tf_idx[i] : gene_idx[i - T];
        int node = num + idx;
        int base = rowstart[node];
        int deg = counts[node];
        const unsigned* hp = Hh + lane;
        float ax = 0.f, ay = 0.f;
        int j = 0;
        for (; j + 4 <= deg; j += 4) {
            int s0 = ssorted[base + j];
            int s1 = ssorted[base + j + 1];
            int s2 = ssorted[base + j + 2];
            int s3 = ssorted[base + j + 3];
            unsigned v0 = hp[(size_t)s0 * 64];
            unsigned v1 = hp[(size_t)s1 * 64];
            unsigned v2 = hp[(size_t)s2 * 64];
            unsigned v3 = hp[(size_t)s3 * 64];
            ax += (lo_bf16(v0) + lo_bf16(v1)) + (lo_bf16(v2) + lo_bf16(v3));
            ay += (hi_bf16(v0) + hi_bf16(v1)) + (hi_bf16(v2) + hi_bf16(v3));
        }
        for (; j < deg; j++) {
            int s = ssorted[base + j];
            unsigned v = hp[(size_t)s * 64];
            ax += lo_bf16(v);
            ay += hi_bf16(v);
        }
        float inv = 1.f / fmaxf((float)deg, 1.f);
        float2 st = {ax * inv, ay * inv};
        *reinterpret_cast<float2*>(&aggS[wv][2 * lane]) = st;
    }
    __syncthreads();
    if (i < ntar) {
        float e = b2[lane];
#pragma unroll 4
        for (int k = 0; k < DIM; k++) e += aggS[wv][k] * W2s[k * DEMB + lane];
        emb[(size_t)i * DEMB + lane] = e;
    }
}

// ------- AB precompute: rows 0..T-1 = tf_emb@Wm1_top + bm1 ; rows T.. = g_emb@Wm1_bot -------

__global__ __launch_bounds__(128) void ab_kernel(const float* __restrict__ emb,
                                                 const float* __restrict__ Wm1,
                                                 const float* __restrict__ bm1,
                                                 float* __restrict__ AB, int T, int ntar) {
    int i = blockIdx.x;
    int j = threadIdx.x;
    if (i >= ntar) return;
    const float* e = emb + (size_t)i * DEMB;
    int base = (i < T) ? 0 : DEMB;
    float acc = (i < T) ? bm1[j] : 0.f;
#pragma unroll 4
    for (int k = 0; k < DEMB; k++) acc += e[k] * Wm1[(size_t)(base + k) * DIM + j];
    AB[(size_t)i * DIM + j] = acc;
}

// ------- final: out[t,g,:] = softmax(relu(tfA[t]+gB[g]) @ Wm2 + bm2) via logit-diff sigmoid -------

__global__ __launch_bounds__(256) void final_kernel(const float* __restrict__ AB,
                                                    const float* __restrict__ Wm2,
                                                    const float* __restrict__ bm2,
                                                    float* __restrict__ out, int T, int G) {
    __shared__ float tfAs[8 * DIM];  // 4 KB
    __shared__ float wd[DIM];        // Wm2[:,0]-Wm2[:,1]
    int tid = threadIdx.x;
    int t0 = blockIdx.y * 8;
    int g0 = blockIdx.x * 256;
    {
        int idx = tid * 4;
        int t = t0 + (idx >> 7);
        float4 v = {0, 0, 0, 0};
        if (t < T) v = *reinterpret_cast<const float4*>(&AB[(size_t)t0 * DIM + idx]);
        *reinterpret_cast<float4*>(&tfAs[idx]) = v;
    }
    if (tid < DIM) wd[tid] = Wm2[tid * 2] - Wm2[tid * 2 + 1];
    __syncthreads();
    int g = g0 + tid;
    int gc = min(g, G - 1);
    const float4* gp = reinterpret_cast<const float4*>(AB + (size_t)(T + gc) * DIM);
    float acc[8];
#pragma unroll
    for (int t = 0; t < 8; t++) acc[t] = 0.f;
    for (int kc = 0; kc < 16; kc++) {
        float4 ga = gp[kc * 2];
        float4 gb = gp[kc * 2 + 1];
        float4 wa = *reinterpret_cast<const float4*>(&wd[kc * 8]);
        float4 wb = *reinterpret_cast<const float4*>(&wd[kc * 8 + 4]);
#pragma unroll
        for (int t = 0; t < 8; t++) {
            const float4 ta = *reinterpret_cast<const float4*>(&tfAs[t * DIM + kc * 8]);
            const float4 tb = *reinterpret_cast<const float4*>(&tfAs[t * DIM + kc * 8 + 4]);
            acc[t] += fmaxf(ta.x + ga.x, 0.f) * wa.x;
            acc[t] += fmaxf(ta.y + ga.y, 0.f) * wa.y;
            acc[t] += fmaxf(ta.z + ga.z, 0.f) * wa.z;
            acc[t] += fmaxf(ta.w + ga.w, 0.f) * wa.w;
            acc[t] += fmaxf(tb.x + gb.x, 0.f) * wb.x;
            acc[t] += fmaxf(tb.y + gb.y, 0.f) * wb.y;
            acc[t] += fmaxf(tb.z + gb.z, 0.f) * wb.z;
            acc[t] += fmaxf(tb.w + gb.w, 0.f) * wb.w;
        }
    }
    if (g < G) {
        float bd = bm2[0] - bm2[1];
#pragma unroll
        for (int t = 0; t < 8; t++) {
            if (t0 + t < T) {
                float d = acc[t] + bd;                // l0 - l1
                float p0 = 1.f / (1.f + __expf(-d));  // softmax_0
                float2 r = {p0, 1.f - p0};
                *reinterpret_cast<float2*>(&out[((size_t)(t0 + t) * G + g) * 2]) = r;
            }
        }
    }
}

// ---------------- launcher ----------------

extern "C" void kernel_launch(void* const* d_in, const int* in_sizes, int n_in,
                              void* d_out, int out_size, void* d_ws, size_t ws_size,
                              hipStream_t stream) {
    const float* x    = (const float*)d_in[0];
    const float* W1   = (const float*)d_in[1];
    const float* b1   = (const float*)d_in[2];
    const float* W2   = (const float*)d_in[3];
    const float* b2   = (const float*)d_in[4];
    const float* Wm1  = (const float*)d_in[5];
    const float* bm1  = (const float*)d_in[6];
    const float* Wm2  = (const float*)d_in[7];
    const float* bm2  = (const float*)d_in[8];
    const int* ei     = (const int*)d_in[9];
    const int* dnum   = (const int*)d_in[10];
    const int* tfidx  = (const int*)d_in[11];
    const int* geidx  = (const int*)d_in[12];
    float* out = (float*)d_out;

    int n_nodes = in_sizes[0] / DIM;
    int n_edges = in_sizes[9] / 2;
    int T = in_sizes[11];
    int G = in_sizes[12];
    int ntar = T + G;
    const int* srcp = ei;
    const int* dstp = ei + n_edges;

    char* w = (char*)d_ws;
    size_t o = 0;
    auto alloc = [&](size_t bytes) {
        void* p = w + o;
        o += (bytes + 255) & ~(size_t)255;
        return p;
    };
    unsigned* xh   = (unsigned*)alloc((size_t)n_nodes * 64 * 4);   // 20.5 MB packed bf16
    unsigned* Hh   = (unsigned*)alloc((size_t)n_nodes * 64 * 4);   // 20.5 MB packed bf16
    float* A       = (float*)alloc((size_t)n_nodes * DIM * 4);     // 41 MB (reused below)
    int* ssorted   = (int*)alloc((size_t)n_edges * 4);             // 10.24 MB
    int* counts    = (int*)alloc((size_t)n_nodes * 4);
    int* rowstart  = (int*)alloc((size_t)n_nodes * 4);
    int* cursor    = (int*)alloc((size_t)n_nodes * 4);
    int* blockoffs = (int*)alloc(4096);
    // overlays on A (A is dead after gemm1): emb (2.1 MB) at A, AB (4.2 MB) at A+8MB
    float* emb = A;
    float* AB  = A + (8u * 1024u * 1024u / 4u);

    hipMemsetAsync(counts, 0, (size_t)n_nodes * 4, stream);

    int ge = (n_edges + 255) / 256;
    int nb = (n_nodes + 255) / 256;
    convert_kernel<<<2048, 256, 0, stream>>>(x, xh, n_nodes * 64);
    count_kernel<<<ge, 256, 0, stream>>>(dstp, counts, n_edges);
    scanA_kernel<<<nb, 256, 0, stream>>>(counts, rowstart, blockoffs, n_nodes);
    scanB_kernel<<<1, 512, 0, stream>>>(blockoffs, nb);
    scanC_kernel<<<nb, 256, 0, stream>>>(rowstart, cursor, blockoffs, n_nodes);
    scatter_kernel<<<ge, 256, 0, stream>>>(srcp, dstp, cursor, ssorted, n_edges);

    agg_kernel<<<(n_nodes + 3) / 4, 256, 0, stream>>>(xh, rowstart, counts, ssorted, A, n_nodes);
    gemm1_kernel<<<(n_nodes + 31) / 32, 256, 0, stream>>>(A, W1, b1, Hh, n_nodes);
    target_kernel<<<(ntar + 3) / 4, 256, 0, stream>>>(Hh, W2, b2, rowstart, counts, ssorted,
                                                      dnum, tfidx, geidx, emb, T, ntar);
    ab_kernel<<<ntar, 128, 0, stream>>>(emb, Wm1, bm1, AB, T, ntar);
    final_kernel<<<dim3((G + 255) / 256, (T + 7) / 8), 256, 0, stream>>>(AB, Wm2, bm2, out, T, G);
}

// Round 3
// 421.055 us; speedup vs baseline: 1.9240x; 1.5802x over previous
//
#include <hip/hip_runtime.h>
#include <math.h>

#define DIM 128
#define DEMB 64
#define CHUNK 8192  // edges per block in bucket_scatter

// ---------------- bf16 pack/unpack helpers ----------------

__device__ __forceinline__ unsigned pack_bf16x2(float a, float b) {
    unsigned ua = __float_as_uint(a);
    unsigned ub = __float_as_uint(b);
    ua = (ua + 0x7fffu + ((ua >> 16) & 1u)) >> 16;          // low half  = bf16(a)
    ub = (ub + 0x7fffu + ((ub >> 16) & 1u)) & 0xffff0000u;  // high half = bf16(b)
    return ua | ub;
}
__device__ __forceinline__ float lo_bf16(unsigned v) { return __uint_as_float(v << 16); }
__device__ __forceinline__ float hi_bf16(unsigned v) { return __uint_as_float(v & 0xffff0000u); }

// ---------------- convert x (f32) -> packed bf16 ----------------

__global__ __launch_bounds__(256) void convert_kernel(const float* __restrict__ in,
                                                      unsigned* __restrict__ out, int n2) {
    int i = blockIdx.x * 256 + threadIdx.x;
    int stride = gridDim.x * 256;
    for (; i < n2; i += stride) {
        float2 v = reinterpret_cast<const float2*>(in)[i];
        out[i] = pack_bf16x2(v.x, v.y);
    }
}

// ---------------- bucketed CSR build ----------------
// bucket b = dst >> 8 (256 nodes/bucket); nbuck = ceil(n_nodes/256) <= 384

__global__ __launch_bounds__(256) void bucket_count(const int* __restrict__ dst,
                                                    int* __restrict__ bcnt,
                                                    int n_edges, int nbuck) {
    __shared__ int h[384];
    for (int i = threadIdx.x; i < nbuck; i += 256) h[i] = 0;
    __syncthreads();
    int i = blockIdx.x * 256 + threadIdx.x;
    int stride = gridDim.x * 256;
    for (; i < n_edges; i += stride) atomicAdd(&h[dst[i] >> 8], 1);
    __syncthreads();
    for (int i2 = threadIdx.x; i2 < nbuck; i2 += 256)
        if (h[i2]) atomicAdd(&bcnt[i2], h[i2]);
}

__global__ __launch_bounds__(512) void bucket_scan(const int* __restrict__ bcnt,
                                                   int* __restrict__ bstart,
                                                   int* __restrict__ bcursor,
                                                   int nbuck, int n_edges) {
    __shared__ int sm[512];
    int tid = threadIdx.x;
    int v = (tid < nbuck) ? bcnt[tid] : 0;
    sm[tid] = v;
    __syncthreads();
    for (int off = 1; off < 512; off <<= 1) {
        int t = (tid >= off) ? sm[tid - off] : 0;
        __syncthreads();
        if (tid >= off) sm[tid] += t;
        __syncthreads();
    }
    if (tid < nbuck) {
        int e = sm[tid] - v;
        bstart[tid] = e;
        bcursor[tid] = e;
    }
    if (tid == 0) bstart[nbuck] = n_edges;
}

// per-block LDS counting sort by bucket, then coalesced copy-out
__global__ __launch_bounds__(256) void bucket_scatter(const int* __restrict__ src,
                                                      const int* __restrict__ dst,
                                                      int* __restrict__ bcursor,
                                                      unsigned* __restrict__ binned,
                                                      int n_edges, int nbuck) {
    __shared__ int cnt[384], off[384], gbase[384], cur[384];
    __shared__ unsigned stage[CHUNK];
    int tid = threadIdx.x;
    int e0 = blockIdx.x * CHUNK;
    int ne = min(CHUNK, n_edges - e0);
    for (int i = tid; i < nbuck; i += 256) cnt[i] = 0;
    __syncthreads();
    for (int j = tid; j < ne; j += 256) atomicAdd(&cnt[dst[e0 + j] >> 8], 1);
    __syncthreads();
    if (tid == 0) {
        int s = 0;
        for (int b = 0; b < nbuck; b++) { off[b] = s; s += cnt[b]; }
    }
    __syncthreads();
    for (int b = tid; b < nbuck; b += 256) {
        cur[b] = off[b];
        gbase[b] = cnt[b] ? atomicAdd(&bcursor[b], cnt[b]) : 0;
    }
    __syncthreads();
    for (int j = tid; j < ne; j += 256) {
        int d = dst[e0 + j];
        int s = src[e0 + j];
        int b = d >> 8;
        int p = atomicAdd(&cur[b], 1);
        stage[p] = ((unsigned)s << 8) | (unsigned)(d & 255);
    }
    __syncthreads();
    int wv = tid >> 6, lane = tid & 63;
    for (int b = wv; b < nbuck; b += 4) {
        int c = cnt[b], o = off[b], g = gbase[b];
        for (int k = lane; k < c; k += 64) binned[g + k] = stage[o + k];
    }
}

// one block per bucket: per-node counts, scan, CSR scatter (all writes L2-local)
__global__ __launch_bounds__(256) void bucket_csr(const unsigned* __restrict__ binned,
                                                  const int* __restrict__ bstart,
                                                  int* __restrict__ counts,
                                                  int* __restrict__ rowstart,
                                                  int* __restrict__ ssorted,
                                                  int n_nodes) {
    __shared__ int sm[256], cur[256];
    __shared__ int cntv[256];
    int b = blockIdx.x;
    int bs = bstart[b], be = bstart[b + 1];
    int node0 = b << 8;
    int tid = threadIdx.x;
    cntv[tid] = 0;
    __syncthreads();
    for (int j = bs + tid; j < be; j += 256) atomicAdd(&cntv[binned[j] & 255u], 1);
    __syncthreads();
    int v = cntv[tid];
    sm[tid] = v;
    __syncthreads();
    for (int off = 1; off < 256; off <<= 1) {
        int t = (tid >= off) ? sm[tid - off] : 0;
        __syncthreads();
        if (tid >= off) sm[tid] += t;
        __syncthreads();
    }
    int excl = sm[tid] - v;
    int node = node0 + tid;
    if (node < n_nodes) {
        counts[node] = v;
        rowstart[node] = bs + excl;
    }
    cur[tid] = excl;
    __syncthreads();
    for (int j = bs + tid; j < be; j += 256) {
        unsigned e = binned[j];
        int p = atomicAdd(&cur[(int)(e & 255u)], 1);
        ssorted[bs + p] = (int)(e >> 8);
    }
}

// ------- GCN layer 1 aggregate: mean over bf16 rows of xh (wave per node) -------

__global__ __launch_bounds__(256) void agg_kernel(const unsigned* __restrict__ xh,
                                                  const int* __restrict__ rowstart,
                                                  const int* __restrict__ counts,
                                                  const int* __restrict__ ssorted,
                                                  float* __restrict__ A, int n_nodes) {
    int wave = (blockIdx.x * 256 + threadIdx.x) >> 6;
    int lane = threadIdx.x & 63;
    if (wave >= n_nodes) return;
    int base = rowstart[wave];
    int deg = counts[wave];
    const unsigned* xp = xh + lane;  // row stride = 64 uints (128 bf16)
    float ax = 0.f, ay = 0.f;
    int j = 0;
    for (; j + 8 <= deg; j += 8) {
        int s0 = ssorted[base + j];
        int s1 = ssorted[base + j + 1];
        int s2 = ssorted[base + j + 2];
        int s3 = ssorted[base + j + 3];
        int s4 = ssorted[base + j + 4];
        int s5 = ssorted[base + j + 5];
        int s6 = ssorted[base + j + 6];
        int s7 = ssorted[base + j + 7];
        unsigned v0 = xp[(size_t)s0 * 64];
        unsigned v1 = xp[(size_t)s1 * 64];
        unsigned v2 = xp[(size_t)s2 * 64];
        unsigned v3 = xp[(size_t)s3 * 64];
        unsigned v4 = xp[(size_t)s4 * 64];
        unsigned v5 = xp[(size_t)s5 * 64];
        unsigned v6 = xp[(size_t)s6 * 64];
        unsigned v7 = xp[(size_t)s7 * 64];
        ax += ((lo_bf16(v0) + lo_bf16(v1)) + (lo_bf16(v2) + lo_bf16(v3))) +
              ((lo_bf16(v4) + lo_bf16(v5)) + (lo_bf16(v6) + lo_bf16(v7)));
        ay += ((hi_bf16(v0) + hi_bf16(v1)) + (hi_bf16(v2) + hi_bf16(v3))) +
              ((hi_bf16(v4) + hi_bf16(v5)) + (hi_bf16(v6) + hi_bf16(v7)));
    }
    for (; j < deg; j++) {
        int s = ssorted[base + j];
        unsigned v = xp[(size_t)s * 64];
        ax += lo_bf16(v);
        ay += hi_bf16(v);
    }
    float inv = 1.f / fmaxf((float)deg, 1.f);
    float2 st = {ax * inv, ay * inv};
    *reinterpret_cast<float2*>(A + (size_t)wave * DIM + 2 * lane) = st;
}

// ------- H = relu(A @ W1 + b1)  (f32 compute, packed-bf16 output) -------

__global__ __launch_bounds__(256) void gemm1_kernel(const float* __restrict__ A,
                                                    const float* __restrict__ W1,
                                                    const float* __restrict__ b1,
                                                    unsigned* __restrict__ Hh, int n_rows) {
    __shared__ float W1s[DIM * DIM];  // 64 KB
    __shared__ float As[32 * DIM];    // 16 KB
    int tid = threadIdx.x;
    for (int i = 0; i < 16; i++) {
        int idx = (i * 256 + tid) * 4;
        *reinterpret_cast<float4*>(&W1s[idx]) = *reinterpret_cast<const float4*>(&W1[idx]);
    }
    int r0 = blockIdx.x * 32;
    for (int i = 0; i < 4; i++) {
        int idx = (i * 256 + tid) * 4;
        int gr = r0 + (idx >> 7);
        float4 vv = {0, 0, 0, 0};
        if (gr < n_rows) vv = *reinterpret_cast<const float4*>(&A[(size_t)r0 * DIM + idx]);
        *reinterpret_cast<float4*>(&As[idx]) = vv;
    }
    __syncthreads();
    int tx = tid & 31, ty = tid >> 5;
    float4 b = *reinterpret_cast<const float4*>(&b1[tx * 4]);
    float acc[4][4];
#pragma unroll
    for (int i = 0; i < 4; i++) {
        acc[i][0] = b.x; acc[i][1] = b.y; acc[i][2] = b.z; acc[i][3] = b.w;
    }
#pragma unroll 8
    for (int kc = 0; kc < 32; kc++) {
        int k = kc * 4;
        float4 w0 = *reinterpret_cast<const float4*>(&W1s[(k + 0) * DIM + tx * 4]);
        float4 w1 = *reinterpret_cast<const float4*>(&W1s[(k + 1) * DIM + tx * 4]);
        float4 w2 = *reinterpret_cast<const float4*>(&W1s[(k + 2) * DIM + tx * 4]);
        float4 w3 = *reinterpret_cast<const float4*>(&W1s[(k + 3) * DIM + tx * 4]);
#pragma unroll
        for (int i = 0; i < 4; i++) {
            float4 a = *reinterpret_cast<const float4*>(&As[(ty * 4 + i) * DIM + k]);
            acc[i][0] += a.x * w0.x; acc[i][1] += a.x * w0.y; acc[i][2] += a.x * w0.z; acc[i][3] += a.x * w0.w;
            acc[i][0] += a.y * w1.x; acc[i][1] += a.y * w1.y; acc[i][2] += a.y * w1.z; acc[i][3] += a.y * w1.w;
            acc[i][0] += a.z * w2.x; acc[i][1] += a.z * w2.y; acc[i][2] += a.z * w2.z; acc[i][3] += a.z * w2.w;
            acc[i][0] += a.w * w3.x; acc[i][1] += a.w * w3.y; acc[i][2] += a.w * w3.z; acc[i][3] += a.w * w3.w;
        }
    }
#pragma unroll
    for (int i = 0; i < 4; i++) {
        int r = r0 + ty * 4 + i;
        if (r < n_rows) {
            float o0 = fmaxf(acc[i][0], 0.f);
            float o1 = fmaxf(acc[i][1], 0.f);
            float o2 = fmaxf(acc[i][2], 0.f);
            float o3 = fmaxf(acc[i][3], 0.f);
            uint2 pk = {pack_bf16x2(o0, o1), pack_bf16x2(o2, o3)};
            *reinterpret_cast<uint2*>(&Hh[(size_t)r * 64 + tx * 2]) = pk;
        }
    }
}

// ------- GCN layer 2 at target nodes only: mean-agg of Hh then @W2 + b2 -------

__global__ __launch_bounds__(256) void target_kernel(const unsigned* __restrict__ Hh,
                                                     const float* __restrict__ W2,
                                                     const float* __restrict__ b2,
                                                     const int* __restrict__ rowstart,
                                                     const int* __restrict__ counts,
                                                     const int* __restrict__ ssorted,
                                                     const int* __restrict__ dnum,
                                                     const int* __restrict__ tf_idx,
                                                     const int* __restrict__ gene_idx,
                                                     float* __restrict__ emb, int T, int ntar) {
    __shared__ float W2s[DIM * DEMB];  // 32 KB
    __shared__ float aggS[4][DIM];
    int tid = threadIdx.x;
    for (int i = 0; i < 8; i++) {
        int idx = (i * 256 + tid) * 4;
        *reinterpret_cast<float4*>(&W2s[idx]) = *reinterpret_cast<const float4*>(&W2[idx]);
    }
    int wv = tid >> 6, lane = tid & 63;
    int i = blockIdx.x * 4 + wv;
    int num = dnum[0];
    if (i < ntar) {
        int idx = (i < T) ? tf_idx[i] : gene_idx[i - T];
        int node = num + idx;
        int base = rowstart[node];
        int deg = counts[node];
        const unsigned* hp = Hh + lane;
        float ax = 0.f, ay = 0.f;
        int j = 0;
        for (; j + 4 <= deg; j += 4) {
            int s0 = ssorted[base + j];
            int s1 = ssorted[base + j + 1];
            int s2 = ssorted[base + j + 2];
            int s3 = ssorted[base + j + 3];
            unsigned v0 = hp[(size_t)s0 * 64];
            unsigned v1 = hp[(size_t)s1 * 64];
            unsigned v2 = hp[(size_t)s2 * 64];
            unsigned v3 = hp[(size_t)s3 * 64];
            ax += (lo_bf16(v0) + lo_bf16(v1)) + (lo_bf16(v2) + lo_bf16(v3));
            ay += (hi_bf16(v0) + hi_bf16(v1)) + (hi_bf16(v2) + hi_bf16(v3));
        }
        for (; j < deg; j++) {
            int s = ssorted[base + j];
            unsigned v = hp[(size_t)s * 64];
            ax += lo_bf16(v);
            ay += hi_bf16(v);
        }
        float inv = 1.f / fmaxf((float)deg, 1.f);
        float2 st = {ax * inv, ay * inv};
        *reinterpret_cast<float2*>(&aggS[wv][2 * lane]) = st;
    }
    __syncthreads();
    if (i < ntar) {
        float e = b2[lane];
#pragma unroll 4
        for (int k = 0; k < DIM; k++) e += aggS[wv][k] * W2s[k * DEMB + lane];
        emb[(size_t)i * DEMB + lane] = e;
    }
}

// ------- AB precompute: rows 0..T-1 = tf_emb@Wm1_top + bm1 ; rows T.. = g_emb@Wm1_bot -------

__global__ __launch_bounds__(128) void ab_kernel(const float* __restrict__ emb,
                                                 const float* __restrict__ Wm1,
                                                 const float* __restrict__ bm1,
                                                 float* __restrict__ AB, int T, int ntar) {
    int i = blockIdx.x;
    int j = threadIdx.x;
    if (i >= ntar) return;
    const float* e = emb + (size_t)i * DEMB;
    int base = (i < T) ? 0 : DEMB;
    float acc = (i < T) ? bm1[j] : 0.f;
#pragma unroll 4
    for (int k = 0; k < DEMB; k++) acc += e[k] * Wm1[(size_t)(base + k) * DIM + j];
    AB[(size_t)i * DIM + j] = acc;
}

// ------- final: out[t,g,:] = softmax via logit-diff sigmoid -------

__global__ __launch_bounds__(256) void final_kernel(const float* __restrict__ AB,
                                                    const float* __restrict__ Wm2,
                                                    const float* __restrict__ bm2,
                                                    float* __restrict__ out, int T, int G) {
    __shared__ float tfAs[8 * DIM];  // 4 KB
    __shared__ float wd[DIM];        // Wm2[:,0]-Wm2[:,1]
    int tid = threadIdx.x;
    int t0 = blockIdx.y * 8;
    int g0 = blockIdx.x * 256;
    {
        int idx = tid * 4;
        int t = t0 + (idx >> 7);
        float4 v = {0, 0, 0, 0};
        if (t < T) v = *reinterpret_cast<const float4*>(&AB[(size_t)t0 * DIM + idx]);
        *reinterpret_cast<float4*>(&tfAs[idx]) = v;
    }
    if (tid < DIM) wd[tid] = Wm2[tid * 2] - Wm2[tid * 2 + 1];
    __syncthreads();
    int g = g0 + tid;
    int gc = min(g, G - 1);
    const float4* gp = reinterpret_cast<const float4*>(AB + (size_t)(T + gc) * DIM);
    float acc[8];
#pragma unroll
    for (int t = 0; t < 8; t++) acc[t] = 0.f;
    for (int kc = 0; kc < 16; kc++) {
        float4 ga = gp[kc * 2];
        float4 gb = gp[kc * 2 + 1];
        float4 wa = *reinterpret_cast<const float4*>(&wd[kc * 8]);
        float4 wb = *reinterpret_cast<const float4*>(&wd[kc * 8 + 4]);
#pragma unroll
        for (int t = 0; t < 8; t++) {
            const float4 ta = *reinterpret_cast<const float4*>(&tfAs[t * DIM + kc * 8]);
            const float4 tb = *reinterpret_cast<const float4*>(&tfAs[t * DIM + kc * 8 + 4]);
            acc[t] += fmaxf(ta.x + ga.x, 0.f) * wa.x;
            acc[t] += fmaxf(ta.y + ga.y, 0.f) * wa.y;
            acc[t] += fmaxf(ta.z + ga.z, 0.f) * wa.z;
            acc[t] += fmaxf(ta.w + ga.w, 0.f) * wa.w;
            acc[t] += fmaxf(tb.x + gb.x, 0.f) * wb.x;
            acc[t] += fmaxf(tb.y + gb.y, 0.f) * wb.y;
            acc[t] += fmaxf(tb.z + gb.z, 0.f) * wb.z;
            acc[t] += fmaxf(tb.w + gb.w, 0.f) * wb.w;
        }
    }
    if (g < G) {
        float bd = bm2[0] - bm2[1];
#pragma unroll
        for (int t = 0; t < 8; t++) {
            if (t0 + t < T) {
                float d = acc[t] + bd;                // l0 - l1
                float p0 = 1.f / (1.f + __expf(-d));  // softmax_0
                float2 r = {p0, 1.f - p0};
                *reinterpret_cast<float2*>(&out[((size_t)(t0 + t) * G + g) * 2]) = r;
            }
        }
    }
}

// ---------------- launcher ----------------

extern "C" void kernel_launch(void* const* d_in, const int* in_sizes, int n_in,
                              void* d_out, int out_size, void* d_ws, size_t ws_size,
                              hipStream_t stream) {
    const float* x    = (const float*)d_in[0];
    const float* W1   = (const float*)d_in[1];
    const float* b1   = (const float*)d_in[2];
    const float* W2   = (const float*)d_in[3];
    const float* b2   = (const float*)d_in[4];
    const float* Wm1  = (const float*)d_in[5];
    const float* bm1  = (const float*)d_in[6];
    const float* Wm2  = (const float*)d_in[7];
    const float* bm2  = (const float*)d_in[8];
    const int* ei     = (const int*)d_in[9];
    const int* dnum   = (const int*)d_in[10];
    const int* tfidx  = (const int*)d_in[11];
    const int* geidx  = (const int*)d_in[12];
    float* out = (float*)d_out;

    int n_nodes = in_sizes[0] / DIM;
    int n_edges = in_sizes[9] / 2;
    int T = in_sizes[11];
    int G = in_sizes[12];
    int ntar = T + G;
    int nbuck = (n_nodes + 255) >> 8;  // 313
    const int* srcp = ei;
    const int* dstp = ei + n_edges;

    char* w = (char*)d_ws;
    size_t o = 0;
    auto alloc = [&](size_t bytes) {
        void* p = w + o;
        o += (bytes + 255) & ~(size_t)255;
        return p;
    };
    unsigned* xh   = (unsigned*)alloc((size_t)n_nodes * 64 * 4);   // 20.5 MB packed bf16
    unsigned* Hh   = (unsigned*)alloc((size_t)n_nodes * 64 * 4);   // 20.5 MB packed bf16
    float* A       = (float*)alloc((size_t)n_nodes * DIM * 4);     // 41 MB (reused below)
    int* ssorted   = (int*)alloc((size_t)n_edges * 4);             // 10.24 MB
    int* counts    = (int*)alloc((size_t)n_nodes * 4);
    int* rowstart  = (int*)alloc((size_t)n_nodes * 4);
    int* bcnt      = (int*)alloc(2048);
    int* bstart    = (int*)alloc(2048);
    int* bcursor   = (int*)alloc(2048);
    // overlays: binned on Hh (dead until gemm1); emb/AB on A (dead after gemm1)
    unsigned* binned = Hh;
    float* emb = A;
    float* AB  = A + (8u * 1024u * 1024u / 4u);

    hipMemsetAsync(bcnt, 0, (size_t)nbuck * 4, stream);

    convert_kernel<<<2048, 256, 0, stream>>>(x, xh, n_nodes * 64);
    bucket_count<<<256, 256, 0, stream>>>(dstp, bcnt, n_edges, nbuck);
    bucket_scan<<<1, 512, 0, stream>>>(bcnt, bstart, bcursor, nbuck, n_edges);
    bucket_scatter<<<(n_edges + CHUNK - 1) / CHUNK, 256, 0, stream>>>(srcp, dstp, bcursor,
                                                                      binned, n_edges, nbuck);
    bucket_csr<<<nbuck, 256, 0, stream>>>(binned, bstart, counts, rowstart, ssorted, n_nodes);

    agg_kernel<<<(n_nodes + 3) / 4, 256, 0, stream>>>(xh, rowstart, counts, ssorted, A, n_nodes);
    gemm1_kernel<<<(n_nodes + 31) / 32, 256, 0, stream>>>(A, W1, b1, Hh, n_nodes);
    target_kernel<<<(ntar + 3) / 4, 256, 0, stream>>>(Hh, W2, b2, rowstart, counts, ssorted,
                                                      dnum, tfidx, geidx, emb, T, ntar);
    ab_kernel<<<ntar, 128, 0, stream>>>(emb, Wm1, bm1, AB, T, ntar);
    final_kernel<<<dim3((G + 255) / 256, (T + 7) / 8), 256, 0, stream>>>(AB, Wm2, bm2, out, T, G);
}

// Round 4
// 411.632 us; speedup vs baseline: 1.9680x; 1.0229x over previous
//
#include <hip/hip_runtime.h>
#include <math.h>

#define DIM 128
#define DEMB 64
#define CHUNK 8192  // edges per block in bucket_scatter

// ---------------- bf16 pack/unpack helpers ----------------

__device__ __forceinline__ unsigned pack_bf16x2(float a, float b) {
    unsigned ua = __float_as_uint(a);
    unsigned ub = __float_as_uint(b);
    ua = (ua + 0x7fffu + ((ua >> 16) & 1u)) >> 16;          // low half  = bf16(a)
    ub = (ub + 0x7fffu + ((ub >> 16) & 1u)) & 0xffff0000u;  // high half = bf16(b)
    return ua | ub;
}
__device__ __forceinline__ float lo_bf16(unsigned v) { return __uint_as_float(v << 16); }
__device__ __forceinline__ float hi_bf16(unsigned v) { return __uint_as_float(v & 0xffff0000u); }

// ---------------- convert x (f32) -> packed bf16 ----------------

__global__ __launch_bounds__(256) void convert_kernel(const float* __restrict__ in,
                                                      unsigned* __restrict__ out, int n2) {
    int i = blockIdx.x * 256 + threadIdx.x;
    int stride = gridDim.x * 256;
    for (; i < n2; i += stride) {
        float2 v = reinterpret_cast<const float2*>(in)[i];
        out[i] = pack_bf16x2(v.x, v.y);
    }
}

// ---------------- bucketed CSR build ----------------
// bucket b = dst >> 8 (256 nodes/bucket); nbuck = ceil(n_nodes/256) <= 384

__global__ __launch_bounds__(256) void bucket_count(const int* __restrict__ dst,
                                                    int* __restrict__ bcnt,
                                                    int n_edges, int nbuck) {
    __shared__ int h[384];
    for (int i = threadIdx.x; i < nbuck; i += 256) h[i] = 0;
    __syncthreads();
    int i = blockIdx.x * 256 + threadIdx.x;
    int stride = gridDim.x * 256;
    for (; i < n_edges; i += stride) atomicAdd(&h[dst[i] >> 8], 1);
    __syncthreads();
    for (int i2 = threadIdx.x; i2 < nbuck; i2 += 256)
        if (h[i2]) atomicAdd(&bcnt[i2], h[i2]);
}

__global__ __launch_bounds__(512) void bucket_scan(const int* __restrict__ bcnt,
                                                   int* __restrict__ bstart,
                                                   int* __restrict__ bcursor,
                                                   int nbuck, int n_edges) {
    __shared__ int sm[512];
    int tid = threadIdx.x;
    int v = (tid < nbuck) ? bcnt[tid] : 0;
    sm[tid] = v;
    __syncthreads();
    for (int off = 1; off < 512; off <<= 1) {
        int t = (tid >= off) ? sm[tid - off] : 0;
        __syncthreads();
        if (tid >= off) sm[tid] += t;
        __syncthreads();
    }
    if (tid < nbuck) {
        int e = sm[tid] - v;
        bstart[tid] = e;
        bcursor[tid] = e;
    }
    if (tid == 0) bstart[nbuck] = n_edges;
}

// per-block LDS counting sort by bucket, element-parallel copy-out
__global__ __launch_bounds__(256) void bucket_scatter(const int* __restrict__ src,
                                                      const int* __restrict__ dst,
                                                      int* __restrict__ bcursor,
                                                      unsigned* __restrict__ binned,
                                                      int n_edges, int nbuck) {
    __shared__ unsigned stage[CHUNK];        // packed (src<<8)|local_dst  (32 KB)
    __shared__ unsigned short bkt[CHUNK];    // bucket id per staged elem  (16 KB)
    __shared__ int cnt[384], off[384], gbase[384], cur[384];
    __shared__ int sc[256];
    __shared__ int tot0;
    int tid = threadIdx.x;
    int e0 = blockIdx.x * CHUNK;
    int ne = min(CHUNK, n_edges - e0);
    for (int i = tid; i < nbuck; i += 256) cnt[i] = 0;
    __syncthreads();
    for (int j = tid; j < ne; j += 256) atomicAdd(&cnt[dst[e0 + j] >> 8], 1);
    __syncthreads();
    // two-chunk parallel exclusive scan of cnt[0..nbuck) -> off
    {
        int v0 = (tid < nbuck) ? cnt[tid] : 0;
        sc[tid] = v0;
        __syncthreads();
        for (int o = 1; o < 256; o <<= 1) {
            int t = (tid >= o) ? sc[tid - o] : 0;
            __syncthreads();
            sc[tid] += t;
            __syncthreads();
        }
        if (tid < nbuck) off[tid] = sc[tid] - v0;
        if (tid == 255) tot0 = sc[255];
        __syncthreads();
        int i1 = 256 + tid;
        int v1 = (i1 < nbuck) ? cnt[i1] : 0;
        sc[tid] = v1;
        __syncthreads();
        for (int o = 1; o < 256; o <<= 1) {
            int t = (tid >= o) ? sc[tid - o] : 0;
            __syncthreads();
            sc[tid] += t;
            __syncthreads();
        }
        if (i1 < nbuck) off[i1] = tot0 + sc[tid] - v1;
        __syncthreads();
    }
    for (int b = tid; b < nbuck; b += 256) {
        cur[b] = off[b];
        gbase[b] = cnt[b] ? atomicAdd(&bcursor[b], cnt[b]) : 0;
    }
    __syncthreads();
    for (int j = tid; j < ne; j += 256) {
        int d = dst[e0 + j];
        int s = src[e0 + j];
        int b = d >> 8;
        int p = atomicAdd(&cur[b], 1);
        stage[p] = ((unsigned)s << 8) | (unsigned)(d & 255);
        bkt[p] = (unsigned short)b;
    }
    __syncthreads();
    for (int j = tid; j < ne; j += 256) {
        int b = bkt[j];
        binned[gbase[b] + (j - off[b])] = stage[j];
    }
}

// one block per bucket: per-node counts, scan, CSR scatter (all writes L2-local)
__global__ __launch_bounds__(256) void bucket_csr(const unsigned* __restrict__ binned,
                                                  const int* __restrict__ bstart,
                                                  int* __restrict__ counts,
                                                  int* __restrict__ rowstart,
                                                  int* __restrict__ ssorted,
                                                  int n_nodes) {
    __shared__ int sm[256], cur[256];
    __shared__ int cntv[256];
    int b = blockIdx.x;
    int bs = bstart[b], be = bstart[b + 1];
    int node0 = b << 8;
    int tid = threadIdx.x;
    cntv[tid] = 0;
    __syncthreads();
    for (int j = bs + tid; j < be; j += 256) atomicAdd(&cntv[binned[j] & 255u], 1);
    __syncthreads();
    int v = cntv[tid];
    sm[tid] = v;
    __syncthreads();
    for (int off = 1; off < 256; off <<= 1) {
        int t = (tid >= off) ? sm[tid - off] : 0;
        __syncthreads();
        if (tid >= off) sm[tid] += t;
        __syncthreads();
    }
    int excl = sm[tid] - v;
    int node = node0 + tid;
    if (node < n_nodes) {
        counts[node] = v;
        rowstart[node] = bs + excl;
    }
    cur[tid] = excl;
    __syncthreads();
    for (int j = bs + tid; j < be; j += 256) {
        unsigned e = binned[j];
        int p = atomicAdd(&cur[(int)(e & 255u)], 1);
        ssorted[bs + p] = (int)(e >> 8);
    }
}

// ------- GCN layer 1 aggregate: mean over bf16 rows of xh, bf16 output (wave per node) -------

__global__ __launch_bounds__(256) void agg_kernel(const unsigned* __restrict__ xh,
                                                  const int* __restrict__ rowstart,
                                                  const int* __restrict__ counts,
                                                  const int* __restrict__ ssorted,
                                                  unsigned* __restrict__ Ah, int n_nodes) {
    int wave = (blockIdx.x * 256 + threadIdx.x) >> 6;
    int lane = threadIdx.x & 63;
    if (wave >= n_nodes) return;
    int base = rowstart[wave];
    int deg = counts[wave];
    const unsigned* xp = xh + lane;  // row stride = 64 uints (128 bf16)
    float ax = 0.f, ay = 0.f;
    int j = 0;
    for (; j + 8 <= deg; j += 8) {
        int s0 = ssorted[base + j];
        int s1 = ssorted[base + j + 1];
        int s2 = ssorted[base + j + 2];
        int s3 = ssorted[base + j + 3];
        int s4 = ssorted[base + j + 4];
        int s5 = ssorted[base + j + 5];
        int s6 = ssorted[base + j + 6];
        int s7 = ssorted[base + j + 7];
        unsigned v0 = xp[(size_t)s0 * 64];
        unsigned v1 = xp[(size_t)s1 * 64];
        unsigned v2 = xp[(size_t)s2 * 64];
        unsigned v3 = xp[(size_t)s3 * 64];
        unsigned v4 = xp[(size_t)s4 * 64];
        unsigned v5 = xp[(size_t)s5 * 64];
        unsigned v6 = xp[(size_t)s6 * 64];
        unsigned v7 = xp[(size_t)s7 * 64];
        ax += ((lo_bf16(v0) + lo_bf16(v1)) + (lo_bf16(v2) + lo_bf16(v3))) +
              ((lo_bf16(v4) + lo_bf16(v5)) + (lo_bf16(v6) + lo_bf16(v7)));
        ay += ((hi_bf16(v0) + hi_bf16(v1)) + (hi_bf16(v2) + hi_bf16(v3))) +
              ((hi_bf16(v4) + hi_bf16(v5)) + (hi_bf16(v6) + hi_bf16(v7)));
    }
    for (; j < deg; j++) {
        int s = ssorted[base + j];
        unsigned v = xp[(size_t)s * 64];
        ax += lo_bf16(v);
        ay += hi_bf16(v);
    }
    float inv = 1.f / fmaxf((float)deg, 1.f);
    Ah[(size_t)wave * 64 + lane] = pack_bf16x2(ax * inv, ay * inv);
}

// ------- H = relu(A @ W1 + b1)  (bf16 A, f32 W1/compute, packed-bf16 output) -------

__global__ __launch_bounds__(256) void gemm1_kernel(const unsigned* __restrict__ Ah,
                                                    const float* __restrict__ W1,
                                                    const float* __restrict__ b1,
                                                    unsigned* __restrict__ Hh, int n_rows) {
    __shared__ float W1s[DIM * DIM];   // 64 KB
    __shared__ unsigned As[32 * 64];   // 8 KB packed bf16
    int tid = threadIdx.x;
    for (int i = 0; i < 16; i++) {
        int idx = (i * 256 + tid) * 4;
        *reinterpret_cast<float4*>(&W1s[idx]) = *reinterpret_cast<const float4*>(&W1[idx]);
    }
    int r0 = blockIdx.x * 32;
    for (int i = 0; i < 2; i++) {
        int idx = (i * 256 + tid) * 4;
        int gr = r0 + (idx >> 6);
        uint4 vv = {0, 0, 0, 0};
        if (gr < n_rows) vv = *reinterpret_cast<const uint4*>(&Ah[(size_t)r0 * 64 + idx]);
        *reinterpret_cast<uint4*>(&As[idx]) = vv;
    }
    __syncthreads();
    int tx = tid & 31, ty = tid >> 5;
    float4 b = *reinterpret_cast<const float4*>(&b1[tx * 4]);
    float acc[4][4];
#pragma unroll
    for (int i = 0; i < 4; i++) {
        acc[i][0] = b.x; acc[i][1] = b.y; acc[i][2] = b.z; acc[i][3] = b.w;
    }
#pragma unroll 8
    for (int kc = 0; kc < 32; kc++) {
        int k = kc * 4;
        float4 w0 = *reinterpret_cast<const float4*>(&W1s[(k + 0) * DIM + tx * 4]);
        float4 w1 = *reinterpret_cast<const float4*>(&W1s[(k + 1) * DIM + tx * 4]);
        float4 w2 = *reinterpret_cast<const float4*>(&W1s[(k + 2) * DIM + tx * 4]);
        float4 w3 = *reinterpret_cast<const float4*>(&W1s[(k + 3) * DIM + tx * 4]);
#pragma unroll
        for (int i = 0; i < 4; i++) {
            uint2 av = *reinterpret_cast<const uint2*>(&As[(ty * 4 + i) * 64 + kc * 2]);
            float a0 = lo_bf16(av.x), a1 = hi_bf16(av.x);
            float a2 = lo_bf16(av.y), a3 = hi_bf16(av.y);
            acc[i][0] += a0 * w0.x; acc[i][1] += a0 * w0.y; acc[i][2] += a0 * w0.z; acc[i][3] += a0 * w0.w;
            acc[i][0] += a1 * w1.x; acc[i][1] += a1 * w1.y; acc[i][2] += a1 * w1.z; acc[i][3] += a1 * w1.w;
            acc[i][0] += a2 * w2.x; acc[i][1] += a2 * w2.y; acc[i][2] += a2 * w2.z; acc[i][3] += a2 * w2.w;
            acc[i][0] += a3 * w3.x; acc[i][1] += a3 * w3.y; acc[i][2] += a3 * w3.z; acc[i][3] += a3 * w3.w;
        }
    }
#pragma unroll
    for (int i = 0; i < 4; i++) {
        int r = r0 + ty * 4 + i;
        if (r < n_rows) {
            float o0 = fmaxf(acc[i][0], 0.f);
            float o1 = fmaxf(acc[i][1], 0.f);
            float o2 = fmaxf(acc[i][2], 0.f);
            float o3 = fmaxf(acc[i][3], 0.f);
            uint2 pk = {pack_bf16x2(o0, o1), pack_bf16x2(o2, o3)};
            *reinterpret_cast<uint2*>(&Hh[(size_t)r * 64 + tx * 2]) = pk;
        }
    }
}

// ------- GCN layer 2 at target nodes only: mean-agg of Hh then @W2 + b2 -------

__global__ __launch_bounds__(256) void target_kernel(const unsigned* __restrict__ Hh,
                                                     const float* __restrict__ W2,
                                                     const float* __restrict__ b2,
                                                     const int* __restrict__ rowstart,
                                                     const int* __restrict__ counts,
                                                     const int* __restrict__ ssorted,
                                                     const int* __restrict__ dnum,
                                                     const int* __restrict__ tf_idx,
                                                     const int* __restrict__ gene_idx,
                                                     float* __restrict__ emb, int T, int ntar) {
    __shared__ float W2s[DIM * DEMB];  // 32 KB
    __shared__ float aggS[4][DIM];
    int tid = threadIdx.x;
    for (int i = 0; i < 8; i++) {
        int idx = (i * 256 + tid) * 4;
        *reinterpret_cast<float4*>(&W2s[idx]) = *reinterpret_cast<const float4*>(&W2[idx]);
    }
    int wv = tid >> 6, lane = tid & 63;
    int i = blockIdx.x * 4 + wv;
    int num = dnum[0];
    if (i < ntar) {
        int idx = (i < T) ? tf_idx[i] : gene_idx[i - T];
        int node = num + idx;
        int base = rowstart[node];
        int deg = counts[node];
        const unsigned* hp = Hh + lane;
        float ax = 0.f, ay = 0.f;
        int j = 0;
        for (; j + 4 <= deg; j += 4) {
            int s0 = ssorted[base + j];
            int s1 = ssorted[base + j + 1];
            int s2 = ssorted[base + j + 2];
            int s3 = ssorted[base + j + 3];
            unsigned v0 = hp[(size_t)s0 * 64];
            unsigned v1 = hp[(size_t)s1 * 64];
            unsigned v2 = hp[(size_t)s2 * 64];
            unsigned v3 = hp[(size_t)s3 * 64];
            ax += (lo_bf16(v0) + lo_bf16(v1)) + (lo_bf16(v2) + lo_bf16(v3));
            ay += (hi_bf16(v0) + hi_bf16(v1)) + (hi_bf16(v2) + hi_bf16(v3));
        }
        for (; j < deg; j++) {
            int s = ssorted[base + j];
            unsigned v = hp[(size_t)s * 64];
            ax += lo_bf16(v);
            ay += hi_bf16(v);
        }
        float inv = 1.f / fmaxf((float)deg, 1.f);
        float2 st = {ax * inv, ay * inv};
        *reinterpret_cast<float2*>(&aggS[wv][2 * lane]) = st;
    }
    __syncthreads();
    if (i < ntar) {
        float e = b2[lane];
#pragma unroll 4
        for (int k = 0; k < DIM; k++) e += aggS[wv][k] * W2s[k * DEMB + lane];
        emb[(size_t)i * DEMB + lane] = e;
    }
}

// ------- AB precompute: rows 0..T-1 = tf_emb@Wm1_top + bm1 ; rows T.. = g_emb@Wm1_bot -------

__global__ __launch_bounds__(128) void ab_kernel(const float* __restrict__ emb,
                                                 const float* __restrict__ Wm1,
                                                 const float* __restrict__ bm1,
                                                 float* __restrict__ AB, int T, int ntar) {
    int i = blockIdx.x;
    int j = threadIdx.x;
    if (i >= ntar) return;
    const float* e = emb + (size_t)i * DEMB;
    int base = (i < T) ? 0 : DEMB;
    float acc = (i < T) ? bm1[j] : 0.f;
#pragma unroll 4
    for (int k = 0; k < DEMB; k++) acc += e[k] * Wm1[(size_t)(base + k) * DIM + j];
    AB[(size_t)i * DIM + j] = acc;
}

// ------- final: out[t,g,:] = softmax via logit-diff sigmoid -------

__global__ __launch_bounds__(256) void final_kernel(const float* __restrict__ AB,
                                                    const float* __restrict__ Wm2,
                                                    const float* __restrict__ bm2,
                                                    float* __restrict__ out, int T, int G) {
    __shared__ float tfAs[8 * DIM];  // 4 KB
    __shared__ float wd[DIM];        // Wm2[:,0]-Wm2[:,1]
    int tid = threadIdx.x;
    int t0 = blockIdx.y * 8;
    int g0 = blockIdx.x * 256;
    {
        int idx = tid * 4;
        int t = t0 + (idx >> 7);
        float4 v = {0, 0, 0, 0};
        if (t < T) v = *reinterpret_cast<const float4*>(&AB[(size_t)t0 * DIM + idx]);
        *reinterpret_cast<float4*>(&tfAs[idx]) = v;
    }
    if (tid < DIM) wd[tid] = Wm2[tid * 2] - Wm2[tid * 2 + 1];
    __syncthreads();
    int g = g0 + tid;
    int gc = min(g, G - 1);
    const float4* gp = reinterpret_cast<const float4*>(AB + (size_t)(T + gc) * DIM);
    float acc[8];
#pragma unroll
    for (int t = 0; t < 8; t++) acc[t] = 0.f;
    for (int kc = 0; kc < 16; kc++) {
        float4 ga = gp[kc * 2];
        float4 gb = gp[kc * 2 + 1];
        float4 wa = *reinterpret_cast<const float4*>(&wd[kc * 8]);
        float4 wb = *reinterpret_cast<const float4*>(&wd[kc * 8 + 4]);
#pragma unroll
        for (int t = 0; t < 8; t++) {
            const float4 ta = *reinterpret_cast<const float4*>(&tfAs[t * DIM + kc * 8]);
            const float4 tb = *reinterpret_cast<const float4*>(&tfAs[t * DIM + kc * 8 + 4]);
            acc[t] += fmaxf(ta.x + ga.x, 0.f) * wa.x;
            acc[t] += fmaxf(ta.y + ga.y, 0.f) * wa.y;
            acc[t] += fmaxf(ta.z + ga.z, 0.f) * wa.z;
            acc[t] += fmaxf(ta.w + ga.w, 0.f) * wa.w;
            acc[t] += fmaxf(tb.x + gb.x, 0.f) * wb.x;
            acc[t] += fmaxf(tb.y + gb.y, 0.f) * wb.y;
            acc[t] += fmaxf(tb.z + gb.z, 0.f) * wb.z;
            acc[t] += fmaxf(tb.w + gb.w, 0.f) * wb.w;
        }
    }
    if (g < G) {
        float bd = bm2[0] - bm2[1];
#pragma unroll
        for (int t = 0; t < 8; t++) {
            if (t0 + t < T) {
                float d = acc[t] + bd;                // l0 - l1
                float p0 = 1.f / (1.f + __expf(-d));  // softmax_0
                float2 r = {p0, 1.f - p0};
                *reinterpret_cast<float2*>(&out[((size_t)(t0 + t) * G + g) * 2]) = r;
            }
        }
    }
}

// ---------------- launcher ----------------

extern "C" void kernel_launch(void* const* d_in, const int* in_sizes, int n_in,
                              void* d_out, int out_size, void* d_ws, size_t ws_size,
                              hipStream_t stream) {
    const float* x    = (const float*)d_in[0];
    const float* W1   = (const float*)d_in[1];
    const float* b1   = (const float*)d_in[2];
    const float* W2   = (const float*)d_in[3];
    const float* b2   = (const float*)d_in[4];
    const float* Wm1  = (const float*)d_in[5];
    const float* bm1  = (const float*)d_in[6];
    const float* Wm2  = (const float*)d_in[7];
    const float* bm2  = (const float*)d_in[8];
    const int* ei     = (const int*)d_in[9];
    const int* dnum   = (const int*)d_in[10];
    const int* tfidx  = (const int*)d_in[11];
    const int* geidx  = (const int*)d_in[12];
    float* out = (float*)d_out;

    int n_nodes = in_sizes[0] / DIM;
    int n_edges = in_sizes[9] / 2;
    int T = in_sizes[11];
    int G = in_sizes[12];
    int ntar = T + G;
    int nbuck = (n_nodes + 255) >> 8;  // 313
    const int* srcp = ei;
    const int* dstp = ei + n_edges;

    char* w = (char*)d_ws;
    size_t o = 0;
    auto alloc = [&](size_t bytes) {
        void* p = w + o;
        o += (bytes + 255) & ~(size_t)255;
        return p;
    };
    unsigned* xh   = (unsigned*)alloc((size_t)n_nodes * 64 * 4);   // 20.5 MB packed bf16
    unsigned* Hh   = (unsigned*)alloc((size_t)n_nodes * 64 * 4);   // 20.5 MB packed bf16
    unsigned* Ah   = (unsigned*)alloc((size_t)n_nodes * 64 * 4);   // 20.5 MB packed bf16
    int* ssorted   = (int*)alloc((size_t)n_edges * 4);             // 10.24 MB
    int* counts    = (int*)alloc((size_t)n_nodes * 4);
    int* rowstart  = (int*)alloc((size_t)n_nodes * 4);
    int* bcnt      = (int*)alloc(2048);
    int* bstart    = (int*)alloc(2048);
    int* bcursor   = (int*)alloc(2048);
    // overlays: binned on Hh (dead until gemm1); emb/AB on Ah (dead after gemm1)
    unsigned* binned = Hh;
    float* emb = (float*)Ah;
    float* AB  = (float*)Ah + (4u * 1024u * 1024u / 4u);

    hipMemsetAsync(bcnt, 0, (size_t)nbuck * 4, stream);

    convert_kernel<<<2048, 256, 0, stream>>>(x, xh, n_nodes * 64);
    bucket_count<<<1024, 256, 0, stream>>>(dstp, bcnt, n_edges, nbuck);
    bucket_scan<<<1, 512, 0, stream>>>(bcnt, bstart, bcursor, nbuck, n_edges);
    bucket_scatter<<<(n_edges + CHUNK - 1) / CHUNK, 256, 0, stream>>>(srcp, dstp, bcursor,
                                                                      binned, n_edges, nbuck);
    bucket_csr<<<nbuck, 256, 0, stream>>>(binned, bstart, counts, rowstart, ssorted, n_nodes);

    agg_kernel<<<(n_nodes + 3) / 4, 256, 0, stream>>>(xh, rowstart, counts, ssorted, Ah, n_nodes);
    gemm1_kernel<<<(n_nodes + 31) / 32, 256, 0, stream>>>(Ah, W1, b1, Hh, n_nodes);
    target_kernel<<<(ntar + 3) / 4, 256, 0, stream>>>(Hh, W2, b2, rowstart, counts, ssorted,
                                                      dnum, tfidx, geidx, emb, T, ntar);
    ab_kernel<<<ntar, 128, 0, stream>>>(emb, Wm1, bm1, AB, T, ntar);
    final_kernel<<<dim3((G + 255) / 256, (T + 7) / 8), 256, 0, stream>>>(AB, Wm2, bm2, out, T, G);
}

// Round 5
// 354.441 us; speedup vs baseline: 2.2856x; 1.1614x over previous
//
#include <hip/hip_runtime.h>
#include <math.h>

#define DIM 128
#define DEMB 64
#define CHUNK 8192  // edges per block in bucket_scatter

typedef __attribute__((ext_vector_type(8))) short bf16x8;
typedef __attribute__((ext_vector_type(4))) float f32x4;

// ---------------- bf16 pack/unpack helpers ----------------

__device__ __forceinline__ unsigned pack_bf16x2(float a, float b) {
    unsigned ua = __float_as_uint(a);
    unsigned ub = __float_as_uint(b);
    ua = (ua + 0x7fffu + ((ua >> 16) & 1u)) >> 16;          // low half  = bf16(a)
    ub = (ub + 0x7fffu + ((ub >> 16) & 1u)) & 0xffff0000u;  // high half = bf16(b)
    return ua | ub;
}
__device__ __forceinline__ float lo_bf16(unsigned v) { return __uint_as_float(v << 16); }
__device__ __forceinline__ float hi_bf16(unsigned v) { return __uint_as_float(v & 0xffff0000u); }

// ---------------- convert x (f32) -> packed bf16 ----------------

__global__ __launch_bounds__(256) void convert_kernel(const float* __restrict__ in,
                                                      unsigned* __restrict__ out, int n2) {
    int i = blockIdx.x * 256 + threadIdx.x;
    int stride = gridDim.x * 256;
    for (; i < n2; i += stride) {
        float2 v = reinterpret_cast<const float2*>(in)[i];
        out[i] = pack_bf16x2(v.x, v.y);
    }
}

// ------- prep: W1 (f32 [k][n]) -> W1t packed bf16, n-major [n][k] (128x64 uints) -------

__global__ __launch_bounds__(256) void prep_w1t(const float* __restrict__ W1,
                                                unsigned* __restrict__ W1t) {
    int i = blockIdx.x * 256 + threadIdx.x;  // [0, 128*64)
    if (i >= 128 * 64) return;
    int n = i >> 6, k2 = i & 63;
    float a = W1[(size_t)(2 * k2) * DIM + n];
    float b = W1[(size_t)(2 * k2 + 1) * DIM + n];
    W1t[i] = pack_bf16x2(a, b);
}

// ---------------- bucketed CSR build ----------------
// bucket b = dst >> 8 (256 nodes/bucket); nbuck = ceil(n_nodes/256) <= 384

__global__ __launch_bounds__(256) void bucket_count(const int* __restrict__ dst,
                                                    int* __restrict__ bcnt,
                                                    int n_edges, int nbuck) {
    __shared__ int h[384];
    for (int i = threadIdx.x; i < nbuck; i += 256) h[i] = 0;
    __syncthreads();
    int i = blockIdx.x * 256 + threadIdx.x;
    int stride = gridDim.x * 256;
    for (; i < n_edges; i += stride) atomicAdd(&h[dst[i] >> 8], 1);
    __syncthreads();
    for (int i2 = threadIdx.x; i2 < nbuck; i2 += 256)
        if (h[i2]) atomicAdd(&bcnt[i2], h[i2]);
}

__global__ __launch_bounds__(512) void bucket_scan(const int* __restrict__ bcnt,
                                                   int* __restrict__ bstart,
                                                   int* __restrict__ bcursor,
                                                   int nbuck, int n_edges) {
    __shared__ int sm[512];
    int tid = threadIdx.x;
    int v = (tid < nbuck) ? bcnt[tid] : 0;
    sm[tid] = v;
    __syncthreads();
    for (int off = 1; off < 512; off <<= 1) {
        int t = (tid >= off) ? sm[tid - off] : 0;
        __syncthreads();
        if (tid >= off) sm[tid] += t;
        __syncthreads();
    }
    if (tid < nbuck) {
        int e = sm[tid] - v;
        bstart[tid] = e;
        bcursor[tid] = e;
    }
    if (tid == 0) bstart[nbuck] = n_edges;
}

// per-block LDS counting sort by bucket, element-parallel copy-out
__global__ __launch_bounds__(256) void bucket_scatter(const int* __restrict__ src,
                                                      const int* __restrict__ dst,
                                                      int* __restrict__ bcursor,
                                                      unsigned* __restrict__ binned,
                                                      int n_edges, int nbuck) {
    __shared__ unsigned stage[CHUNK];        // packed (src<<8)|local_dst  (32 KB)
    __shared__ unsigned short bkt[CHUNK];    // bucket id per staged elem  (16 KB)
    __shared__ int cnt[384], off[384], gbase[384], cur[384];
    __shared__ int sc[256];
    __shared__ int tot0;
    int tid = threadIdx.x;
    int e0 = blockIdx.x * CHUNK;
    int ne = min(CHUNK, n_edges - e0);
    for (int i = tid; i < nbuck; i += 256) cnt[i] = 0;
    __syncthreads();
    for (int j = tid; j < ne; j += 256) atomicAdd(&cnt[dst[e0 + j] >> 8], 1);
    __syncthreads();
    // two-chunk parallel exclusive scan of cnt[0..nbuck) -> off
    {
        int v0 = (tid < nbuck) ? cnt[tid] : 0;
        sc[tid] = v0;
        __syncthreads();
        for (int o = 1; o < 256; o <<= 1) {
            int t = (tid >= o) ? sc[tid - o] : 0;
            __syncthreads();
            sc[tid] += t;
            __syncthreads();
        }
        if (tid < nbuck) off[tid] = sc[tid] - v0;
        if (tid == 255) tot0 = sc[255];
        __syncthreads();
        int i1 = 256 + tid;
        int v1 = (i1 < nbuck) ? cnt[i1] : 0;
        sc[tid] = v1;
        __syncthreads();
        for (int o = 1; o < 256; o <<= 1) {
            int t = (tid >= o) ? sc[tid - o] : 0;
            __syncthreads();
            sc[tid] += t;
            __syncthreads();
        }
        if (i1 < nbuck) off[i1] = tot0 + sc[tid] - v1;
        __syncthreads();
    }
    for (int b = tid; b < nbuck; b += 256) {
        cur[b] = off[b];
        gbase[b] = cnt[b] ? atomicAdd(&bcursor[b], cnt[b]) : 0;
    }
    __syncthreads();
    for (int j = tid; j < ne; j += 256) {
        int d = dst[e0 + j];
        int s = src[e0 + j];
        int b = d >> 8;
        int p = atomicAdd(&cur[b], 1);
        stage[p] = ((unsigned)s << 8) | (unsigned)(d & 255);
        bkt[p] = (unsigned short)b;
    }
    __syncthreads();
    for (int j = tid; j < ne; j += 256) {
        int b = bkt[j];
        binned[gbase[b] + (j - off[b])] = stage[j];
    }
}

// one block per bucket: counting sort by (dst_local, src_tile) -> CSR with src-tiled
// neighbor lists (src>>13 = 2 MB tiles), so agg's gather sweeps a small moving window.
__global__ __launch_bounds__(256) void bucket_csr(const unsigned* __restrict__ binned,
                                                  const int* __restrict__ bstart,
                                                  int* __restrict__ counts,
                                                  int* __restrict__ rowstart,
                                                  int* __restrict__ ssorted,
                                                  int n_nodes) {
    __shared__ int hist[4096];  // key = (dst_local<<4) | (src>>13)
    __shared__ int psum[256];
    int b = blockIdx.x;
    int bs = bstart[b], be = bstart[b + 1];
    int node0 = b << 8;
    int tid = threadIdx.x;
    for (int i = tid; i < 4096; i += 256) hist[i] = 0;
    __syncthreads();
    for (int j = bs + tid; j < be; j += 256) {
        unsigned e = binned[j];
        int key = (int)((e & 255u) << 4) | (int)((e >> 8) >> 13);
        atomicAdd(&hist[key], 1);
    }
    __syncthreads();
    // thread tid owns node tid's 16 bins
    int loc[16];
    int s = 0;
#pragma unroll
    for (int k = 0; k < 16; k++) {
        loc[k] = s;
        s += hist[tid * 16 + k];
    }
    psum[tid] = s;
    __syncthreads();
    int v = psum[tid];
    int acc = v;
    // Hillis-Steele inclusive scan in psum
    for (int o = 1; o < 256; o <<= 1) {
        int t = (tid >= o) ? psum[tid - o] : 0;
        __syncthreads();
        psum[tid] += t;
        __syncthreads();
    }
    int excl = psum[tid] - v;
    (void)acc;
#pragma unroll
    for (int k = 0; k < 16; k++) hist[tid * 16 + k] = excl + loc[k];
    int node = node0 + tid;
    if (node < n_nodes) {
        counts[node] = s;
        rowstart[node] = bs + excl;
    }
    __syncthreads();
    for (int j = bs + tid; j < be; j += 256) {
        unsigned e = binned[j];
        int key = (int)((e & 255u) << 4) | (int)((e >> 8) >> 13);
        int p = atomicAdd(&hist[key], 1);
        ssorted[bs + p] = (int)(e >> 8);
    }
}

// ------- GCN layer 1 aggregate: mean over bf16 rows of xh, bf16 output (wave per node) -------

__global__ __launch_bounds__(256) void agg_kernel(const unsigned* __restrict__ xh,
                                                  const int* __restrict__ rowstart,
                                                  const int* __restrict__ counts,
                                                  const int* __restrict__ ssorted,
                                                  unsigned* __restrict__ Ah, int n_nodes) {
    int wave = (blockIdx.x * 256 + threadIdx.x) >> 6;
    int lane = threadIdx.x & 63;
    if (wave >= n_nodes) return;
    int base = rowstart[wave];
    int deg = counts[wave];
    const unsigned* xp = xh + lane;  // row stride = 64 uints (128 bf16)
    float ax = 0.f, ay = 0.f;
    int j = 0;
    for (; j + 8 <= deg; j += 8) {
        int s0 = ssorted[base + j];
        int s1 = ssorted[base + j + 1];
        int s2 = ssorted[base + j + 2];
        int s3 = ssorted[base + j + 3];
        int s4 = ssorted[base + j + 4];
        int s5 = ssorted[base + j + 5];
        int s6 = ssorted[base + j + 6];
        int s7 = ssorted[base + j + 7];
        unsigned v0 = xp[(size_t)s0 * 64];
        unsigned v1 = xp[(size_t)s1 * 64];
        unsigned v2 = xp[(size_t)s2 * 64];
        unsigned v3 = xp[(size_t)s3 * 64];
        unsigned v4 = xp[(size_t)s4 * 64];
        unsigned v5 = xp[(size_t)s5 * 64];
        unsigned v6 = xp[(size_t)s6 * 64];
        unsigned v7 = xp[(size_t)s7 * 64];
        ax += ((lo_bf16(v0) + lo_bf16(v1)) + (lo_bf16(v2) + lo_bf16(v3))) +
              ((lo_bf16(v4) + lo_bf16(v5)) + (lo_bf16(v6) + lo_bf16(v7)));
        ay += ((hi_bf16(v0) + hi_bf16(v1)) + (hi_bf16(v2) + hi_bf16(v3))) +
              ((hi_bf16(v4) + hi_bf16(v5)) + (hi_bf16(v6) + hi_bf16(v7)));
    }
    for (; j < deg; j++) {
        int s = ssorted[base + j];
        unsigned v = xp[(size_t)s * 64];
        ax += lo_bf16(v);
        ay += hi_bf16(v);
    }
    float inv = 1.f / fmaxf((float)deg, 1.f);
    Ah[(size_t)wave * 64 + lane] = pack_bf16x2(ax * inv, ay * inv);
}

// ------- H = relu(A @ W1 + b1) via MFMA (bf16 in, f32 acc, bf16 out) -------
// 64 rows/block, 4 waves: wave w owns rows [w*16, w*16+16).
// A-frag: a[j] = A[l&15][s*32 + (l>>4)*8 + j]   (from global, uint4/lane)
// B-frag: b[j] = W1[k][n] = W1t[n][k], lane reads W1t[nt*16+(l&15)][s*32+(l>>4)*8+j]
// C/D  : row = (l>>4)*4 + j, col = nt*16 + (l&15)   [m89-verified mapping]

__global__ __launch_bounds__(256) void gemm1_mfma(const unsigned* __restrict__ Ah,
                                                  const unsigned* __restrict__ W1t,
                                                  const float* __restrict__ b1,
                                                  unsigned* __restrict__ Hh, int n_rows) {
    __shared__ unsigned Wt[128 * 68];  // [n][k2] padded: 64 data + 4 pad uints per row (34 KB)
    int tid = threadIdx.x;
#pragma unroll
    for (int i = 0; i < 32; i++) {
        int idx = i * 256 + tid;  // 0..8191
        Wt[(idx >> 6) * 68 + (idx & 63)] = W1t[idx];
    }
    __syncthreads();
    int wv = tid >> 6, l = tid & 63;
    int r0w = blockIdx.x * 64 + wv * 16;
    int arow = r0w + (l & 15);
    int arowc = min(arow, n_rows - 1);
    int kgrp = l >> 4;
    const bf16x8* ap = reinterpret_cast<const bf16x8*>(Ah + (size_t)arowc * 64);
    bf16x8 afrag[4];
#pragma unroll
    for (int s = 0; s < 4; s++) afrag[s] = ap[s * 4 + kgrp];

    f32x4 acc[8];
#pragma unroll
    for (int nt = 0; nt < 8; nt++) {
        float bias = b1[nt * 16 + (l & 15)];
        acc[nt] = {bias, bias, bias, bias};
    }
#pragma unroll
    for (int s = 0; s < 4; s++) {
#pragma unroll
        for (int nt = 0; nt < 8; nt++) {
            bf16x8 bfrag = *reinterpret_cast<const bf16x8*>(
                &Wt[(nt * 16 + (l & 15)) * 68 + s * 16 + kgrp * 4]);
            acc[nt] = __builtin_amdgcn_mfma_f32_16x16x32_bf16(afrag[s], bfrag, acc[nt], 0, 0, 0);
        }
    }
    // epilogue: relu, pair-pack via shfl_xor(1), even lanes store u32
    bool even = (l & 1) == 0;
#pragma unroll
    for (int nt = 0; nt < 8; nt++) {
#pragma unroll
        for (int j = 0; j < 4; j++) {
            float v = fmaxf(acc[nt][j], 0.f);
            float vp = __shfl_xor(v, 1);
            int r = r0w + ((l >> 4) << 2) + j;
            if (even && r < n_rows) {
                Hh[(size_t)r * 64 + nt * 8 + ((l & 15) >> 1)] = pack_bf16x2(v, vp);
            }
        }
    }
}

// ------- GCN layer 2 at target nodes only: mean-agg of Hh then @W2 + b2 -------

__global__ __launch_bounds__(256) void target_kernel(const unsigned* __restrict__ Hh,
                                                     const float* __restrict__ W2,
                                                     const float* __restrict__ b2,
                                                     const int* __restrict__ rowstart,
                                                     const int* __restrict__ counts,
                                                     const int* __restrict__ ssorted,
                                                     const int* __restrict__ dnum,
                                                     const int* __restrict__ tf_idx,
                                                     const int* __restrict__ gene_idx,
                                                     float* __restrict__ emb, int T, int ntar) {
    __shared__ float W2s[DIM * DEMB];  // 32 KB
    __shared__ float aggS[4][DIM];
    int tid = threadIdx.x;
    for (int i = 0; i < 8; i++) {
        int idx = (i * 256 + tid) * 4;
        *reinterpret_cast<float4*>(&W2s[idx]) = *reinterpret_cast<const float4*>(&W2[idx]);
    }
    int wv = tid >> 6, lane = tid & 63;
    int i = blockIdx.x * 4 + wv;
    int num = dnum[0];
    if (i < ntar) {
        int idx = (i < T) ? tf_idx[i] : gene_idx[i - T];
        int node = num + idx;
        int base = rowstart[node];
        int deg = counts[node];
        const unsigned* hp = Hh + lane;
        float ax = 0.f, ay = 0.f;
        int j = 0;
        for (; j + 4 <= deg; j += 4) {
            int s0 = ssorted[base + j];
            int s1 = ssorted[base + j + 1];
            int s2 = ssorted[base + j + 2];
            int s3 = ssorted[base + j + 3];
            unsigned v0 = hp[(size_t)s0 * 64];
            unsigned v1 = hp[(size_t)s1 * 64];
            unsigned v2 = hp[(size_t)s2 * 64];
            unsigned v3 = hp[(size_t)s3 * 64];
            ax += (lo_bf16(v0) + lo_bf16(v1)) + (lo_bf16(v2) + lo_bf16(v3));
            ay += (hi_bf16(v0) + hi_bf16(v1)) + (hi_bf16(v2) + hi_bf16(v3));
        }
        for (; j < deg; j++) {
            int s = ssorted[base + j];
            unsigned v = hp[(size_t)s * 64];
            ax += lo_bf16(v);
            ay += hi_bf16(v);
        }
        float inv = 1.f / fmaxf((float)deg, 1.f);
        float2 st = {ax * inv, ay * inv};
        *reinterpret_cast<float2*>(&aggS[wv][2 * lane]) = st;
    }
    __syncthreads();
    if (i < ntar) {
        float e = b2[lane];
#pragma unroll 4
        for (int k = 0; k < DIM; k++) e += aggS[wv][k] * W2s[k * DEMB + lane];
        emb[(size_t)i * DEMB + lane] = e;
    }
}

// ------- AB precompute: rows 0..T-1 = tf_emb@Wm1_top + bm1 ; rows T.. = g_emb@Wm1_bot -------

__global__ __launch_bounds__(128) void ab_kernel(const float* __restrict__ emb,
                                                 const float* __restrict__ Wm1,
                                                 const float* __restrict__ bm1,
                                                 float* __restrict__ AB, int T, int ntar) {
    int i = blockIdx.x;
    int j = threadIdx.x;
    if (i >= ntar) return;
    const float* e = emb + (size_t)i * DEMB;
    int base = (i < T) ? 0 : DEMB;
    float acc = (i < T) ? bm1[j] : 0.f;
#pragma unroll 4
    for (int k = 0; k < DEMB; k++) acc += e[k] * Wm1[(size_t)(base + k) * DIM + j];
    AB[(size_t)i * DIM + j] = acc;
}

// ------- final: out[t,g,:] = softmax via logit-diff sigmoid -------

__global__ __launch_bounds__(256) void final_kernel(const float* __restrict__ AB,
                                                    const float* __restrict__ Wm2,
                                                    const float* __restrict__ bm2,
                                                    float* __restrict__ out, int T, int G) {
    __shared__ float tfAs[8 * DIM];  // 4 KB
    __shared__ float wd[DIM];        // Wm2[:,0]-Wm2[:,1]
    int tid = threadIdx.x;
    int t0 = blockIdx.y * 8;
    int g0 = blockIdx.x * 256;
    {
        int idx = tid * 4;
        int t = t0 + (idx >> 7);
        float4 v = {0, 0, 0, 0};
        if (t < T) v = *reinterpret_cast<const float4*>(&AB[(size_t)t0 * DIM + idx]);
        *reinterpret_cast<float4*>(&tfAs[idx]) = v;
    }
    if (tid < DIM) wd[tid] = Wm2[tid * 2] - Wm2[tid * 2 + 1];
    __syncthreads();
    int g = g0 + tid;
    int gc = min(g, G - 1);
    const float4* gp = reinterpret_cast<const float4*>(AB + (size_t)(T + gc) * DIM);
    float acc[8];
#pragma unroll
    for (int t = 0; t < 8; t++) acc[t] = 0.f;
    for (int kc = 0; kc < 16; kc++) {
        float4 ga = gp[kc * 2];
        float4 gb = gp[kc * 2 + 1];
        float4 wa = *reinterpret_cast<const float4*>(&wd[kc * 8]);
        float4 wb = *reinterpret_cast<const float4*>(&wd[kc * 8 + 4]);
#pragma unroll
        for (int t = 0; t < 8; t++) {
            const float4 ta = *reinterpret_cast<const float4*>(&tfAs[t * DIM + kc * 8]);
            const float4 tb = *reinterpret_cast<const float4*>(&tfAs[t * DIM + kc * 8 + 4]);
            acc[t] += fmaxf(ta.x + ga.x, 0.f) * wa.x;
            acc[t] += fmaxf(ta.y + ga.y, 0.f) * wa.y;
            acc[t] += fmaxf(ta.z + ga.z, 0.f) * wa.z;
            acc[t] += fmaxf(ta.w + ga.w, 0.f) * wa.w;
            acc[t] += fmaxf(tb.x + gb.x, 0.f) * wb.x;
            acc[t] += fmaxf(tb.y + gb.y, 0.f) * wb.y;
            acc[t] += fmaxf(tb.z + gb.z, 0.f) * wb.z;
            acc[t] += fmaxf(tb.w + gb.w, 0.f) * wb.w;
        }
    }
    if (g < G) {
        float bd = bm2[0] - bm2[1];
#pragma unroll
        for (int t = 0; t < 8; t++) {
            if (t0 + t < T) {
                float d = acc[t] + bd;                // l0 - l1
                float p0 = 1.f / (1.f + __expf(-d));  // softmax_0
                float2 r = {p0, 1.f - p0};
                *reinterpret_cast<float2*>(&out[((size_t)(t0 + t) * G + g) * 2]) = r;
            }
        }
    }
}

// ---------------- launcher ----------------

extern "C" void kernel_launch(void* const* d_in, const int* in_sizes, int n_in,
                              void* d_out, int out_size, void* d_ws, size_t ws_size,
                              hipStream_t stream) {
    const float* x    = (const float*)d_in[0];
    const float* W1   = (const float*)d_in[1];
    const float* b1   = (const float*)d_in[2];
    const float* W2   = (const float*)d_in[3];
    const float* b2   = (const float*)d_in[4];
    const float* Wm1  = (const float*)d_in[5];
    const float* bm1  = (const float*)d_in[6];
    const float* Wm2  = (const float*)d_in[7];
    const float* bm2  = (const float*)d_in[8];
    const int* ei     = (const int*)d_in[9];
    const int* dnum   = (const int*)d_in[10];
    const int* tfidx  = (const int*)d_in[11];
    const int* geidx  = (const int*)d_in[12];
    float* out = (float*)d_out;

    int n_nodes = in_sizes[0] / DIM;
    int n_edges = in_sizes[9] / 2;
    int T = in_sizes[11];
    int G = in_sizes[12];
    int ntar = T + G;
    int nbuck = (n_nodes + 255) >> 8;  // 313
    const int* srcp = ei;
    const int* dstp = ei + n_edges;

    char* w = (char*)d_ws;
    size_t o = 0;
    auto alloc = [&](size_t bytes) {
        void* p = w + o;
        o += (bytes + 255) & ~(size_t)255;
        return p;
    };
    unsigned* xh   = (unsigned*)alloc((size_t)n_nodes * 64 * 4);   // 20.5 MB packed bf16
    unsigned* Hh   = (unsigned*)alloc((size_t)n_nodes * 64 * 4);   // 20.5 MB packed bf16
    unsigned* Ah   = (unsigned*)alloc((size_t)n_nodes * 64 * 4);   // 20.5 MB packed bf16
    int* ssorted   = (int*)alloc((size_t)n_edges * 4);             // 10.24 MB
    int* counts    = (int*)alloc((size_t)n_nodes * 4);
    int* rowstart  = (int*)alloc((size_t)n_nodes * 4);
    unsigned* W1t  = (unsigned*)alloc(128 * 64 * 4);               // 32 KB bf16 W1^T
    int* bcnt      = (int*)alloc(2048);
    int* bstart    = (int*)alloc(2048);
    int* bcursor   = (int*)alloc(2048);
    // overlays: binned on Hh (dead until gemm1); emb/AB on Ah (dead after gemm1)
    unsigned* binned = Hh;
    float* emb = (float*)Ah;
    float* AB  = (float*)Ah + (4u * 1024u * 1024u / 4u);

    hipMemsetAsync(bcnt, 0, (size_t)nbuck * 4, stream);

    convert_kernel<<<2048, 256, 0, stream>>>(x, xh, n_nodes * 64);
    prep_w1t<<<32, 256, 0, stream>>>(W1, W1t);
    bucket_count<<<1024, 256, 0, stream>>>(dstp, bcnt, n_edges, nbuck);
    bucket_scan<<<1, 512, 0, stream>>>(bcnt, bstart, bcursor, nbuck, n_edges);
    bucket_scatter<<<(n_edges + CHUNK - 1) / CHUNK, 256, 0, stream>>>(srcp, dstp, bcursor,
                                                                      binned, n_edges, nbuck);
    bucket_csr<<<nbuck, 256, 0, stream>>>(binned, bstart, counts, rowstart, ssorted, n_nodes);

    agg_kernel<<<(n_nodes + 3) / 4, 256, 0, stream>>>(xh, rowstart, counts, ssorted, Ah, n_nodes);
    gemm1_mfma<<<(n_nodes + 63) / 64, 256, 0, stream>>>(Ah, W1t, b1, Hh, n_nodes);
    target_kernel<<<(ntar + 3) / 4, 256, 0, stream>>>(Hh, W2, b2, rowstart, counts, ssorted,
                                                      dnum, tfidx, geidx, emb, T, ntar);
    ab_kernel<<<ntar, 128, 0, stream>>>(emb, Wm1, bm1, AB, T, ntar);
    final_kernel<<<dim3((G + 255) / 256, (T + 7) / 8), 256, 0, stream>>>(AB, Wm2, bm2, out, T, G);
}

// Round 6
// 348.115 us; speedup vs baseline: 2.3271x; 1.0182x over previous
//
#include <hip/hip_runtime.h>
#include <math.h>

#define DIM 128
#define DEMB 64
#define CHUNK 8192  // edges per block in bucket_scatter

typedef __attribute__((ext_vector_type(8))) short bf16x8;
typedef __attribute__((ext_vector_type(4))) float f32x4;

// ---------------- bf16 pack/unpack helpers ----------------

__device__ __forceinline__ unsigned pack_bf16x2(float a, float b) {
    unsigned ua = __float_as_uint(a);
    unsigned ub = __float_as_uint(b);
    ua = (ua + 0x7fffu + ((ua >> 16) & 1u)) >> 16;          // low half  = bf16(a)
    ub = (ub + 0x7fffu + ((ub >> 16) & 1u)) & 0xffff0000u;  // high half = bf16(b)
    return ua | ub;
}
__device__ __forceinline__ float lo_bf16(unsigned v) { return __uint_as_float(v << 16); }
__device__ __forceinline__ float hi_bf16(unsigned v) { return __uint_as_float(v & 0xffff0000u); }

// ---------------- convert x (f32) -> packed bf16 ----------------

__global__ __launch_bounds__(256) void convert_kernel(const float* __restrict__ in,
                                                      unsigned* __restrict__ out, int n4) {
    int i = blockIdx.x * 256 + threadIdx.x;
    int stride = gridDim.x * 256;
    for (; i < n4; i += stride) {
        float4 v = reinterpret_cast<const float4*>(in)[i];
        uint2 pk = {pack_bf16x2(v.x, v.y), pack_bf16x2(v.z, v.w)};
        reinterpret_cast<uint2*>(out)[i] = pk;
    }
}

// ------- prep: W1 (f32 [k][n]) -> W1t packed bf16, n-major [n][k] (128x64 uints) -------

__global__ __launch_bounds__(256) void prep_w1t(const float* __restrict__ W1,
                                                unsigned* __restrict__ W1t) {
    int i = blockIdx.x * 256 + threadIdx.x;  // [0, 128*64)
    if (i >= 128 * 64) return;
    int n = i >> 6, k2 = i & 63;
    float a = W1[(size_t)(2 * k2) * DIM + n];
    float b = W1[(size_t)(2 * k2 + 1) * DIM + n];
    W1t[i] = pack_bf16x2(a, b);
}

// ---------------- bucketed CSR build ----------------
// bucket b = dst >> 8 (256 nodes/bucket); nbuck = ceil(n_nodes/256) <= 384

__global__ __launch_bounds__(256) void bucket_count(const int* __restrict__ dst,
                                                    int* __restrict__ bcnt,
                                                    int n_edges, int nbuck) {
    __shared__ int h[384];
    for (int i = threadIdx.x; i < nbuck; i += 256) h[i] = 0;
    __syncthreads();
    int i = blockIdx.x * 256 + threadIdx.x;
    int stride = gridDim.x * 256;
    for (; i < n_edges; i += stride) atomicAdd(&h[dst[i] >> 8], 1);
    __syncthreads();
    for (int i2 = threadIdx.x; i2 < nbuck; i2 += 256)
        if (h[i2]) atomicAdd(&bcnt[i2], h[i2]);
}

__global__ __launch_bounds__(512) void bucket_scan(const int* __restrict__ bcnt,
                                                   int* __restrict__ bstart,
                                                   int* __restrict__ bcursor,
                                                   int nbuck, int n_edges) {
    __shared__ int sm[512];
    int tid = threadIdx.x;
    int v = (tid < nbuck) ? bcnt[tid] : 0;
    sm[tid] = v;
    __syncthreads();
    for (int off = 1; off < 512; off <<= 1) {
        int t = (tid >= off) ? sm[tid - off] : 0;
        __syncthreads();
        if (tid >= off) sm[tid] += t;
        __syncthreads();
    }
    if (tid < nbuck) {
        int e = sm[tid] - v;
        bstart[tid] = e;
        bcursor[tid] = e;
    }
    if (tid == 0) bstart[nbuck] = n_edges;
}

// direct ranked scatter: count -> reserve -> rank+write. Per block, each bucket's
// ~26 edges land in one contiguous window written at once -> L2 merges lines.
__global__ __launch_bounds__(256) void bucket_scatter(const int* __restrict__ src,
                                                      const int* __restrict__ dst,
                                                      int* __restrict__ bcursor,
                                                      unsigned* __restrict__ binned,
                                                      int n_edges, int nbuck) {
    __shared__ int cnt[384], base[384];
    int tid = threadIdx.x;
    int e0 = blockIdx.x * CHUNK;
    int ne = min(CHUNK, n_edges - e0);
    for (int i = tid; i < nbuck; i += 256) cnt[i] = 0;
    __syncthreads();
    for (int j = tid; j < ne; j += 256) atomicAdd(&cnt[dst[e0 + j] >> 8], 1);
    __syncthreads();
    for (int b = tid; b < nbuck; b += 256) {
        int c = cnt[b];
        base[b] = c ? atomicAdd(&bcursor[b], c) : 0;
        cnt[b] = 0;
    }
    __syncthreads();
    for (int j = tid; j < ne; j += 256) {
        int d = dst[e0 + j];
        int s = src[e0 + j];
        int b = d >> 8;
        int r = atomicAdd(&cnt[b], 1);
        binned[base[b] + r] = ((unsigned)s << 8) | (unsigned)(d & 255);
    }
}

// one block per bucket: per-node counts, scan, CSR scatter (all writes L2-local)
__global__ __launch_bounds__(256) void bucket_csr(const unsigned* __restrict__ binned,
                                                  const int* __restrict__ bstart,
                                                  int* __restrict__ counts,
                                                  int* __restrict__ rowstart,
                                                  int* __restrict__ ssorted,
                                                  int n_nodes) {
    __shared__ int sm[256], cur[256];
    __shared__ int cntv[256];
    int b = blockIdx.x;
    int bs = bstart[b], be = bstart[b + 1];
    int node0 = b << 8;
    int tid = threadIdx.x;
    cntv[tid] = 0;
    __syncthreads();
    for (int j = bs + tid; j < be; j += 256) atomicAdd(&cntv[binned[j] & 255u], 1);
    __syncthreads();
    int v = cntv[tid];
    sm[tid] = v;
    __syncthreads();
    for (int off = 1; off < 256; off <<= 1) {
        int t = (tid >= off) ? sm[tid - off] : 0;
        __syncthreads();
        if (tid >= off) sm[tid] += t;
        __syncthreads();
    }
    int excl = sm[tid] - v;
    int node = node0 + tid;
    if (node < n_nodes) {
        counts[node] = v;
        rowstart[node] = bs + excl;
    }
    cur[tid] = excl;
    __syncthreads();
    for (int j = bs + tid; j < be; j += 256) {
        unsigned e = binned[j];
        int p = atomicAdd(&cur[(int)(e & 255u)], 1);
        ssorted[bs + p] = (int)(e >> 8);
    }
}

// ------- GCN layer 1 aggregate: masked unroll-8, bf16 in/out (wave per node) -------

__global__ __launch_bounds__(256) void agg_kernel(const unsigned* __restrict__ xh,
                                                  const int* __restrict__ rowstart,
                                                  const int* __restrict__ counts,
                                                  const int* __restrict__ ssorted,
                                                  unsigned* __restrict__ Ah, int n_nodes) {
    int wave = (blockIdx.x * 256 + threadIdx.x) >> 6;
    int lane = threadIdx.x & 63;
    if (wave >= n_nodes) return;
    int base = rowstart[wave];
    int deg = counts[wave];
    const unsigned* xp = xh + lane;  // row stride = 64 uints (128 bf16)
    float ax = 0.f, ay = 0.f;
    int dm1 = deg - 1;
    for (int j0 = 0; j0 < deg; j0 += 8) {
        unsigned vv[8];
#pragma unroll
        for (int k = 0; k < 8; k++) {
            int s = ssorted[base + min(j0 + k, dm1)];
            vv[k] = xp[(size_t)s * 64];
        }
#pragma unroll
        for (int k = 0; k < 8; k++) {
            unsigned m = (j0 + k <= dm1) ? vv[k] : 0u;
            ax += lo_bf16(m);
            ay += hi_bf16(m);
        }
    }
    float inv = 1.f / fmaxf((float)deg, 1.f);
    Ah[(size_t)wave * 64 + lane] = pack_bf16x2(ax * inv, ay * inv);
}

// ------- H = relu(A @ W1 + b1) via MFMA (bf16 in, f32 acc, bf16 out) -------

__global__ __launch_bounds__(256) void gemm1_mfma(const unsigned* __restrict__ Ah,
                                                  const unsigned* __restrict__ W1t,
                                                  const float* __restrict__ b1,
                                                  unsigned* __restrict__ Hh, int n_rows) {
    __shared__ unsigned Wt[128 * 68];  // [n][k2] padded (34 KB)
    int tid = threadIdx.x;
#pragma unroll
    for (int i = 0; i < 32; i++) {
        int idx = i * 256 + tid;  // 0..8191
        Wt[(idx >> 6) * 68 + (idx & 63)] = W1t[idx];
    }
    __syncthreads();
    int wv = tid >> 6, l = tid & 63;
    int r0w = blockIdx.x * 64 + wv * 16;
    int arow = r0w + (l & 15);
    int arowc = min(arow, n_rows - 1);
    int kgrp = l >> 4;
    const bf16x8* ap = reinterpret_cast<const bf16x8*>(Ah + (size_t)arowc * 64);
    bf16x8 afrag[4];
#pragma unroll
    for (int s = 0; s < 4; s++) afrag[s] = ap[s * 4 + kgrp];

    f32x4 acc[8];
#pragma unroll
    for (int nt = 0; nt < 8; nt++) {
        float bias = b1[nt * 16 + (l & 15)];
        acc[nt] = {bias, bias, bias, bias};
    }
#pragma unroll
    for (int s = 0; s < 4; s++) {
#pragma unroll
        for (int nt = 0; nt < 8; nt++) {
            bf16x8 bfrag = *reinterpret_cast<const bf16x8*>(
                &Wt[(nt * 16 + (l & 15)) * 68 + s * 16 + kgrp * 4]);
            acc[nt] = __builtin_amdgcn_mfma_f32_16x16x32_bf16(afrag[s], bfrag, acc[nt], 0, 0, 0);
        }
    }
    bool even = (l & 1) == 0;
#pragma unroll
    for (int nt = 0; nt < 8; nt++) {
#pragma unroll
        for (int j = 0; j < 4; j++) {
            float v = fmaxf(acc[nt][j], 0.f);
            float vp = __shfl_xor(v, 1);
            int r = r0w + ((l >> 4) << 2) + j;
            if (even && r < n_rows) {
                Hh[(size_t)r * 64 + nt * 8 + ((l & 15) >> 1)] = pack_bf16x2(v, vp);
            }
        }
    }
}

// ------- GCN layer 2 at target nodes only: mean-agg of Hh then @W2 + b2 -------

__global__ __launch_bounds__(256) void target_kernel(const unsigned* __restrict__ Hh,
                                                     const float* __restrict__ W2,
                                                     const float* __restrict__ b2,
                                                     const int* __restrict__ rowstart,
                                                     const int* __restrict__ counts,
                                                     const int* __restrict__ ssorted,
                                                     const int* __restrict__ dnum,
                                                     const int* __restrict__ tf_idx,
                                                     const int* __restrict__ gene_idx,
                                                     float* __restrict__ emb, int T, int ntar) {
    __shared__ float W2s[DIM * DEMB];  // 32 KB
    __shared__ float aggS[4][DIM];
    int tid = threadIdx.x;
    for (int i = 0; i < 8; i++) {
        int idx = (i * 256 + tid) * 4;
        *reinterpret_cast<float4*>(&W2s[idx]) = *reinterpret_cast<const float4*>(&W2[idx]);
    }
    int wv = tid >> 6, lane = tid & 63;
    int i = blockIdx.x * 4 + wv;
    int num = dnum[0];
    if (i < ntar) {
        int idx = (i < T) ? tf_idx[i] : gene_idx[i - T];
        int node = num + idx;
        int base = rowstart[node];
        int deg = counts[node];
        const unsigned* hp = Hh + lane;
        float ax = 0.f, ay = 0.f;
        int dm1 = deg - 1;
        for (int j0 = 0; j0 < deg; j0 += 8) {
            unsigned vv[8];
#pragma unroll
            for (int k = 0; k < 8; k++) {
                int s = ssorted[base + min(j0 + k, dm1)];
                vv[k] = hp[(size_t)s * 64];
            }
#pragma unroll
            for (int k = 0; k < 8; k++) {
                unsigned m = (j0 + k <= dm1) ? vv[k] : 0u;
                ax += lo_bf16(m);
                ay += hi_bf16(m);
            }
        }
        float inv = 1.f / fmaxf((float)deg, 1.f);
        float2 st = {ax * inv, ay * inv};
        *reinterpret_cast<float2*>(&aggS[wv][2 * lane]) = st;
    }
    __syncthreads();
    if (i < ntar) {
        float e = b2[lane];
#pragma unroll 4
        for (int k = 0; k < DIM; k++) e += aggS[wv][k] * W2s[k * DEMB + lane];
        emb[(size_t)i * DEMB + lane] = e;
    }
}

// ------- AB precompute: rows 0..T-1 = tf_emb@Wm1_top + bm1 ; rows T.. = g_emb@Wm1_bot -------

__global__ __launch_bounds__(128) void ab_kernel(const float* __restrict__ emb,
                                                 const float* __restrict__ Wm1,
                                                 const float* __restrict__ bm1,
                                                 float* __restrict__ AB, int T, int ntar) {
    int i = blockIdx.x;
    int j = threadIdx.x;
    if (i >= ntar) return;
    const float* e = emb + (size_t)i * DEMB;
    int base = (i < T) ? 0 : DEMB;
    float acc = (i < T) ? bm1[j] : 0.f;
#pragma unroll 4
    for (int k = 0; k < DEMB; k++) acc += e[k] * Wm1[(size_t)(base + k) * DIM + j];
    AB[(size_t)i * DIM + j] = acc;
}

// ------- final: out[t,g,:] = softmax via logit-diff sigmoid -------

__global__ __launch_bounds__(256) void final_kernel(const float* __restrict__ AB,
                                                    const float* __restrict__ Wm2,
                                                    const float* __restrict__ bm2,
                                                    float* __restrict__ out, int T, int G) {
    __shared__ float tfAs[8 * DIM];  // 4 KB
    __shared__ float wd[DIM];        // Wm2[:,0]-Wm2[:,1]
    int tid = threadIdx.x;
    int t0 = blockIdx.y * 8;
    int g0 = blockIdx.x * 256;
    {
        int idx = tid * 4;
        int t = t0 + (idx >> 7);
        float4 v = {0, 0, 0, 0};
        if (t < T) v = *reinterpret_cast<const float4*>(&AB[(size_t)t0 * DIM + idx]);
        *reinterpret_cast<float4*>(&tfAs[idx]) = v;
    }
    if (tid < DIM) wd[tid] = Wm2[tid * 2] - Wm2[tid * 2 + 1];
    __syncthreads();
    int g = g0 + tid;
    int gc = min(g, G - 1);
    const float4* gp = reinterpret_cast<const float4*>(AB + (size_t)(T + gc) * DIM);
    float acc[8];
#pragma unroll
    for (int t = 0; t < 8; t++) acc[t] = 0.f;
    for (int kc = 0; kc < 16; kc++) {
        float4 ga = gp[kc * 2];
        float4 gb = gp[kc * 2 + 1];
        float4 wa = *reinterpret_cast<const float4*>(&wd[kc * 8]);
        float4 wb = *reinterpret_cast<const float4*>(&wd[kc * 8 + 4]);
#pragma unroll
        for (int t = 0; t < 8; t++) {
            const float4 ta = *reinterpret_cast<const float4*>(&tfAs[t * DIM + kc * 8]);
            const float4 tb = *reinterpret_cast<const float4*>(&tfAs[t * DIM + kc * 8 + 4]);
            acc[t] += fmaxf(ta.x + ga.x, 0.f) * wa.x;
            acc[t] += fmaxf(ta.y + ga.y, 0.f) * wa.y;
            acc[t] += fmaxf(ta.z + ga.z, 0.f) * wa.z;
            acc[t] += fmaxf(ta.w + ga.w, 0.f) * wa.w;
            acc[t] += fmaxf(tb.x + gb.x, 0.f) * wb.x;
            acc[t] += fmaxf(tb.y + gb.y, 0.f) * wb.y;
            acc[t] += fmaxf(tb.z + gb.z, 0.f) * wb.z;
            acc[t] += fmaxf(tb.w + gb.w, 0.f) * wb.w;
        }
    }
    if (g < G) {
        float bd = bm2[0] - bm2[1];
#pragma unroll
        for (int t = 0; t < 8; t++) {
            if (t0 + t < T) {
                float d = acc[t] + bd;                // l0 - l1
                float p0 = 1.f / (1.f + __expf(-d));  // softmax_0
                float2 r = {p0, 1.f - p0};
                *reinterpret_cast<float2*>(&out[((size_t)(t0 + t) * G + g) * 2]) = r;
            }
        }
    }
}

// ---------------- launcher ----------------

extern "C" void kernel_launch(void* const* d_in, const int* in_sizes, int n_in,
                              void* d_out, int out_size, void* d_ws, size_t ws_size,
                              hipStream_t stream) {
    const float* x    = (const float*)d_in[0];
    const float* W1   = (const float*)d_in[1];
    const float* b1   = (const float*)d_in[2];
    const float* W2   = (const float*)d_in[3];
    const float* b2   = (const float*)d_in[4];
    const float* Wm1  = (const float*)d_in[5];
    const float* bm1  = (const float*)d_in[6];
    const float* Wm2  = (const float*)d_in[7];
    const float* bm2  = (const float*)d_in[8];
    const int* ei     = (const int*)d_in[9];
    const int* dnum   = (const int*)d_in[10];
    const int* tfidx  = (const int*)d_in[11];
    const int* geidx  = (const int*)d_in[12];
    float* out = (float*)d_out;

    int n_nodes = in_sizes[0] / DIM;
    int n_edges = in_sizes[9] / 2;
    int T = in_sizes[11];
    int G = in_sizes[12];
    int ntar = T + G;
    int nbuck = (n_nodes + 255) >> 8;  // 313
    const int* srcp = ei;
    const int* dstp = ei + n_edges;

    char* w = (char*)d_ws;
    size_t o = 0;
    auto alloc = [&](size_t bytes) {
        void* p = w + o;
        o += (bytes + 255) & ~(size_t)255;
        return p;
    };
    unsigned* xh   = (unsigned*)alloc((size_t)n_nodes * 64 * 4);   // 20.5 MB packed bf16
    unsigned* Hh   = (unsigned*)alloc((size_t)n_nodes * 64 * 4);   // 20.5 MB packed bf16
    unsigned* Ah   = (unsigned*)alloc((size_t)n_nodes * 64 * 4);   // 20.5 MB packed bf16
    int* ssorted   = (int*)alloc((size_t)n_edges * 4);             // 10.24 MB
    int* counts    = (int*)alloc((size_t)n_nodes * 4);
    int* rowstart  = (int*)alloc((size_t)n_nodes * 4);
    unsigned* W1t  = (unsigned*)alloc(128 * 64 * 4);               // 32 KB bf16 W1^T
    int* bcnt      = (int*)alloc(2048);
    int* bstart    = (int*)alloc(2048);
    int* bcursor   = (int*)alloc(2048);
    // overlays: binned on Hh (dead until gemm1); emb/AB on Ah (dead after gemm1)
    unsigned* binned = Hh;
    float* emb = (float*)Ah;
    float* AB  = (float*)Ah + (4u * 1024u * 1024u / 4u);

    hipMemsetAsync(bcnt, 0, (size_t)nbuck * 4, stream);

    convert_kernel<<<2048, 256, 0, stream>>>(x, xh, n_nodes * 32);
    prep_w1t<<<32, 256, 0, stream>>>(W1, W1t);
    bucket_count<<<1024, 256, 0, stream>>>(dstp, bcnt, n_edges, nbuck);
    bucket_scan<<<1, 512, 0, stream>>>(bcnt, bstart, bcursor, nbuck, n_edges);
    bucket_scatter<<<(n_edges + CHUNK - 1) / CHUNK, 256, 0, stream>>>(srcp, dstp, bcursor,
                                                                      binned, n_edges, nbuck);
    bucket_csr<<<nbuck, 256, 0, stream>>>(binned, bstart, counts, rowstart, ssorted, n_nodes);

    agg_kernel<<<(n_nodes + 3) / 4, 256, 0, stream>>>(xh, rowstart, counts, ssorted, Ah, n_nodes);
    gemm1_mfma<<<(n_nodes + 63) / 64, 256, 0, stream>>>(Ah, W1t, b1, Hh, n_nodes);
    target_kernel<<<(ntar + 3) / 4, 256, 0, stream>>>(Hh, W2, b2, rowstart, counts, ssorted,
                                                      dnum, tfidx, geidx, emb, T, ntar);
    ab_kernel<<<ntar, 128, 0, stream>>>(emb, Wm1, bm1, AB, T, ntar);
    final_kernel<<<dim3((G + 255) / 256, (T + 7) / 8), 256, 0, stream>>>(AB, Wm2, bm2, out, T, G);
}